// Round 2
// baseline (503.860 us; speedup 1.0000x reference)
//
#include <hip/hip_runtime.h>
#include <hip/hip_bf16.h>

// ResUpBlock via bf16 MFMA implicit GEMM (fp32 accumulate).
//   xT  = channels-last bf16 copy of x              [8][64][64][256]
//   t1  = lrelu(conv3x3(x,w1/48)+b1)*sqrt2 -> bf16  [8][64][64][256] (channels-last)
//   t2  = conv1x1(x, wsk/16)              -> bf16   [8][64][64][128] (channels-last)
//   u   = upsample2x(t1)                  -> bf16   [8][128][128][256] (k_synthu)
//   out = lrelu(conv3x3(u,w2/48)+b2) + up2(t2)/sqrt2  (k_conv2u, skip fused in epilogue)
// GEMM mapping (conv1/conv2u): C[m=oc][n=px], A=weights [oc][tap][c] (global, L2-hot),
// B=data channels-last tiles in LDS (c-chunks of 32, padded to 40 -> conflict-free b128).
// mfma_f32_16x16x32_bf16: A/B frag = 8 contiguous k per lane (k=quad*8+j, lane&15=m/n),
// C/D: col=lane&15, row=quad*4+reg (verified layouts per guide m89/m120).
// Fallback: if ws_size < u-buffer needs, use old k_upskip + u-in-LDS k_conv2 path.

typedef __attribute__((ext_vector_type(8))) short bf16x8;
typedef __attribute__((ext_vector_type(4))) float f32x4;

#define SQRT2F  1.41421356237309504880f
#define RSQRT2F 0.70710678118654752440f

__device__ __forceinline__ float lrelu_s(float v) { return v >= 0.f ? v : 0.2f * v; }

__device__ __forceinline__ unsigned short f2bf(float f) {
    unsigned u = __builtin_bit_cast(unsigned, f);
    u += 0x7fffu + ((u >> 16) & 1u);          // RNE
    return (unsigned short)(u >> 16);
}
__device__ __forceinline__ float bflo(unsigned u) {
    return __builtin_bit_cast(float, u << 16);
}
__device__ __forceinline__ float bfhi(unsigned u) {
    return __builtin_bit_cast(float, u & 0xffff0000u);
}

// bilinear 2x coefficients (align_corners=False, matches jax.image.resize; edge-clamped)
__device__ __forceinline__ void up2_coef(int o, int lim, int& i0, int& i1, float& w0, float& w1) {
    int h = o >> 1;
    if (o & 1) { i0 = h; i1 = (h + 1 > lim) ? lim : h + 1; w0 = 0.75f; w1 = 0.25f; }
    else       { i0 = (h - 1 < 0) ? 0 : h - 1; i1 = h;     w0 = 0.25f; w1 = 0.75f; }
}

// ---------------------------------------------------------------------------
// weight transforms
// ---------------------------------------------------------------------------
__global__ __launch_bounds__(256) void k_wt3(const float* __restrict__ w,
                                             unsigned short* __restrict__ wt,
                                             int total, float scale) {
    int i = blockIdx.x * 256 + threadIdx.x;           // i over OC*9*256, layout [oc][tap][c]
    if (i >= total) return;
    int c = i & 255; int rem = i >> 8; int tap = rem % 9; int oc = rem / 9;
    wt[i] = f2bf(w[(oc * 256 + c) * 9 + tap] * scale);
}

__global__ __launch_bounds__(256) void k_wt1(const float* __restrict__ w,
                                             unsigned short* __restrict__ wt,
                                             int total, float scale) {
    int i = blockIdx.x * 256 + threadIdx.x;           // [oc][c] identity layout
    if (i >= total) return;
    wt[i] = f2bf(w[i] * scale);
}

// ---------------------------------------------------------------------------
// x (NCHW f32) -> xT (channels-last bf16) via LDS transpose
// grid (64 px-tiles, 4 c-tiles, 8 n)
// ---------------------------------------------------------------------------
__global__ __launch_bounds__(256) void k_xprep(const float* __restrict__ x,
                                               unsigned short* __restrict__ xT) {
    __shared__ float t[64][65];
    const int n = blockIdx.z, c0 = blockIdx.y << 6, p0 = blockIdx.x << 6;
    for (int i = threadIdx.x; i < 4096; i += 256) {
        int c = i >> 6, p = i & 63;
        t[c][p] = x[((size_t)(n * 256 + c0 + c) << 12) + p0 + p];
    }
    __syncthreads();
    for (int i = threadIdx.x; i < 4096; i += 256) {
        int p = i >> 6, c = i & 63;
        xT[((size_t)((n << 12) + p0 + p) << 8) + c0 + c] = f2bf(t[c][p]);
    }
}

// ---------------------------------------------------------------------------
// conv1: t1 = lrelu(conv3x3(x)+b1)*sqrt2, bf16 channels-last.
// block: M=64 oc x N=256 px (4 rows x 64 cols); wave w owns row y0+w.
// grid dim3(128, 4): bx -> (n, ytile), by -> oc-block
// ---------------------------------------------------------------------------
__global__ __launch_bounds__(256, 2) void k_conv1(
    const unsigned short* __restrict__ xT, const unsigned short* __restrict__ w1T,
    const float* __restrict__ b1, unsigned short* __restrict__ t1)
{
    __shared__ __align__(16) unsigned short dt[6][66][40];   // 31.7 KB, c padded 32->40
    const int tid = threadIdx.x;
    const int n   = blockIdx.x >> 4;
    const int y0  = (blockIdx.x & 15) << 2;
    const int oc0 = blockIdx.y << 6;
    const int w   = tid >> 6;
    const int m   = tid & 15;
    const int q   = (tid & 63) >> 4;

    f32x4 acc[4][4];
#pragma unroll
    for (int a = 0; a < 4; ++a)
#pragma unroll
        for (int g = 0; g < 4; ++g) acc[a][g] = (f32x4){0.f, 0.f, 0.f, 0.f};

    const unsigned short* wbase = w1T + (oc0 + m) * 2304 + (q << 3);

    for (int c0 = 0; c0 < 256; c0 += 32) {
        // stage data tile: rows y0-1..y0+4, cols -1..64, 32 channels (vec8 groups)
        for (int idx = tid; idx < 1584; idx += 256) {
            int r = idx / 264; int rem = idx - r * 264; int col = rem >> 2; int g = rem & 3;
            int gy = y0 - 1 + r, gx = col - 1;
            uint4 v = make_uint4(0, 0, 0, 0);
            if ((unsigned)gy < 64u && (unsigned)gx < 64u)
                v = *(const uint4*)(xT + (((n << 12) + (gy << 6) + gx) << 8) + c0 + (g << 3));
            *(uint4*)(&dt[r][col][g << 3]) = v;
        }
        __syncthreads();

        uint4 aq[2][4];
#pragma unroll
        for (int a = 0; a < 4; ++a)
            aq[0][a] = *(const uint4*)(wbase + a * (16 * 2304) + c0);   // tap 0
#pragma unroll
        for (int tap = 0; tap < 9; ++tap) {
            const int cur = tap & 1;
            if (tap < 8) {
#pragma unroll
                for (int a = 0; a < 4; ++a)
                    aq[cur ^ 1][a] = *(const uint4*)(wbase + a * (16 * 2304) + (tap + 1) * 256 + c0);
            }
            const int dy = tap / 3, dx = tap - 3 * (tap / 3);
            bf16x8 bfr[4];
#pragma unroll
            for (int g = 0; g < 4; ++g)
                bfr[g] = *(const bf16x8*)(&dt[w + dy][(g << 4) + m + dx][q << 3]);
#pragma unroll
            for (int a = 0; a < 4; ++a) {
                bf16x8 af = __builtin_bit_cast(bf16x8, aq[cur][a]);
#pragma unroll
                for (int g = 0; g < 4; ++g)
                    acc[a][g] = __builtin_amdgcn_mfma_f32_16x16x32_bf16(af, bfr[g], acc[a][g], 0, 0, 0);
            }
        }
        __syncthreads();
    }

    // epilogue: lane holds 4 consecutive oc (q*4+r) at px (g*16+m) -> 8B bf16 stores
    const int y = y0 + w;
#pragma unroll
    for (int a = 0; a < 4; ++a) {
        const int oc = oc0 + (a << 4) + (q << 2);
        float b0 = b1[oc], b1v = b1[oc + 1], b2v = b1[oc + 2], b3 = b1[oc + 3];
#pragma unroll
        for (int g = 0; g < 4; ++g) {
            const int xcol = (g << 4) + m;
            unsigned lo = (unsigned)f2bf(lrelu_s(acc[a][g][0] + b0) * SQRT2F)
                        | ((unsigned)f2bf(lrelu_s(acc[a][g][1] + b1v) * SQRT2F) << 16);
            unsigned hi = (unsigned)f2bf(lrelu_s(acc[a][g][2] + b2v) * SQRT2F)
                        | ((unsigned)f2bf(lrelu_s(acc[a][g][3] + b3) * SQRT2F) << 16);
            uint2 s; s.x = lo; s.y = hi;
            *(uint2*)(t1 + (((n << 12) + (y << 6) + xcol) << 8) + oc) = s;
        }
    }
}

// ---------------------------------------------------------------------------
// skip GEMM: t2[px][oc] = sum_c xT[px][c]*wsT[oc][c]  (M=px so stores are oc-runs)
// block: 64 px (wave=16 px) x 128 oc; grid 512
// ---------------------------------------------------------------------------
__global__ __launch_bounds__(256, 2) void k_skip(
    const unsigned short* __restrict__ xT, const unsigned short* __restrict__ wsT,
    unsigned short* __restrict__ t2)
{
    const int tid = threadIdx.x;
    const int w = tid >> 6, m = tid & 15, q = (tid & 63) >> 4;
    const int px0 = blockIdx.x << 6;
    const int apx = px0 + (w << 4) + m;

    f32x4 acc[8];
#pragma unroll
    for (int g = 0; g < 8; ++g) acc[g] = (f32x4){0.f, 0.f, 0.f, 0.f};

#pragma unroll
    for (int c0 = 0; c0 < 256; c0 += 32) {
        bf16x8 af = *(const bf16x8*)(xT + ((size_t)apx << 8) + c0 + (q << 3));
#pragma unroll
        for (int g = 0; g < 8; ++g) {
            bf16x8 bf = *(const bf16x8*)(wsT + (((g << 4) + m) << 8) + c0 + (q << 3));
            acc[g] = __builtin_amdgcn_mfma_f32_16x16x32_bf16(af, bf, acc[g], 0, 0, 0);
        }
    }
#pragma unroll
    for (int g = 0; g < 8; ++g) {
        const int oc = (g << 4) + m;
#pragma unroll
        for (int r = 0; r < 4; ++r) {
            int opx = px0 + (w << 4) + (q << 2) + r;
            t2[((size_t)opx << 7) + oc] = f2bf(acc[g][r]);
        }
    }
}

// ---------------------------------------------------------------------------
// k_synthu: u[n][oy][ox][c] = bilinear2x(t1), bf16 channels-last.
// grid dim3(2, 128, 8): (ox-tile of 64, oy, n); 256 threads, 8 idx each.
// ---------------------------------------------------------------------------
__global__ __launch_bounds__(256) void k_synthu(
    const unsigned short* __restrict__ t1, unsigned short* __restrict__ u)
{
    const int n = blockIdx.z, oy = blockIdx.y, x0 = blockIdx.x << 6;
    int ry0, ry1; float wy0, wy1;
    up2_coef(oy, 63, ry0, ry1, wy0, wy1);
    const unsigned short* tb = t1 + ((size_t)n << 20);           // n*4096*256
    unsigned short* ub = u + ((size_t)((n << 7) + oy) << 15);    // row = 128*256 elems

    for (int idx = threadIdx.x; idx < 2048; idx += 256) {
        const int ox = x0 + (idx >> 5), g = idx & 31;
        int cx0, cx1; float wx0, wx1;
        up2_coef(ox, 63, cx0, cx1, wx0, wx1);
        const int co = g << 3;
        uint4 v00 = *(const uint4*)(tb + (((ry0 << 6) + cx0) << 8) + co);
        uint4 v01 = *(const uint4*)(tb + (((ry0 << 6) + cx1) << 8) + co);
        uint4 v10 = *(const uint4*)(tb + (((ry1 << 6) + cx0) << 8) + co);
        uint4 v11 = *(const uint4*)(tb + (((ry1 << 6) + cx1) << 8) + co);
        const unsigned* pa = (const unsigned*)&v00; const unsigned* pb = (const unsigned*)&v01;
        const unsigned* pc = (const unsigned*)&v10; const unsigned* pd = (const unsigned*)&v11;
        uint4 res; unsigned* pr = (unsigned*)&res;
#pragma unroll
        for (int j = 0; j < 4; ++j) {
            float vlo = wy0 * (wx0 * bflo(pa[j]) + wx1 * bflo(pb[j]))
                      + wy1 * (wx0 * bflo(pc[j]) + wx1 * bflo(pd[j]));
            float vhi = wy0 * (wx0 * bfhi(pa[j]) + wx1 * bfhi(pb[j]))
                      + wy1 * (wx0 * bfhi(pc[j]) + wx1 * bfhi(pd[j]));
            pr[j] = (unsigned)f2bf(vlo) | ((unsigned)f2bf(vhi) << 16);
        }
        *(uint4*)(ub + (ox << 8) + co) = res;
    }
}

// ---------------------------------------------------------------------------
// k_conv2u: out = lrelu(conv3x3(u)+b2) + up2(t2)*RSQRT2, standard zero-padded
// implicit GEMM over u (clone of k_conv1 inner loop; skip fused in epilogue).
// block: M=64 oc x N=256 px (4 oy rows x 64 ox cols)
// grid dim3(512, 2): bx -> (n, ytile(32), xhalf(2)), by -> oc-block
// ---------------------------------------------------------------------------
__global__ __launch_bounds__(256, 2) void k_conv2u(
    const unsigned short* __restrict__ u, const unsigned short* __restrict__ w2T,
    const unsigned short* __restrict__ t2, const float* __restrict__ b2,
    float* __restrict__ out)
{
    __shared__ __align__(16) unsigned short dt[6][66][40];   // 31.7 KB
    const int tid  = threadIdx.x;
    const int n    = blockIdx.x >> 6;
    const int rest = blockIdx.x & 63;
    const int oy0  = (rest >> 1) << 2;
    const int x0   = (rest & 1) << 6;
    const int oc0  = blockIdx.y << 6;
    const int w    = tid >> 6;
    const int m    = tid & 15;
    const int q    = (tid & 63) >> 4;

    f32x4 acc[4][4];
#pragma unroll
    for (int a = 0; a < 4; ++a)
#pragma unroll
        for (int g = 0; g < 4; ++g) acc[a][g] = (f32x4){0.f, 0.f, 0.f, 0.f};

    const unsigned short* wbase = w2T + (oc0 + m) * 2304 + (q << 3);
    const unsigned short* ub    = u + ((size_t)n << 22);     // n*16384*256

    for (int c0 = 0; c0 < 256; c0 += 32) {
        // stage u tile: rows oy0-1..oy0+4, cols x0-1..x0+64, 32 channels
        for (int idx = tid; idx < 1584; idx += 256) {
            int r = idx / 264; int rem = idx - r * 264; int col = rem >> 2; int g = rem & 3;
            int gy = oy0 - 1 + r, gx = x0 - 1 + col;
            uint4 v = make_uint4(0, 0, 0, 0);
            if ((unsigned)gy < 128u && (unsigned)gx < 128u)
                v = *(const uint4*)(ub + (((gy << 7) + gx) << 8) + c0 + (g << 3));
            *(uint4*)(&dt[r][col][g << 3]) = v;
        }
        __syncthreads();

        uint4 aq[2][4];
#pragma unroll
        for (int a = 0; a < 4; ++a)
            aq[0][a] = *(const uint4*)(wbase + a * (16 * 2304) + c0);
#pragma unroll
        for (int tap = 0; tap < 9; ++tap) {
            const int cur = tap & 1;
            if (tap < 8) {
#pragma unroll
                for (int a = 0; a < 4; ++a)
                    aq[cur ^ 1][a] = *(const uint4*)(wbase + a * (16 * 2304) + (tap + 1) * 256 + c0);
            }
            const int dy = tap / 3, dx = tap - 3 * (tap / 3);
            bf16x8 bfr[4];
#pragma unroll
            for (int g = 0; g < 4; ++g)
                bfr[g] = *(const bf16x8*)(&dt[w + dy][(g << 4) + m + dx][q << 3]);
#pragma unroll
            for (int a = 0; a < 4; ++a) {
                bf16x8 af = __builtin_bit_cast(bf16x8, aq[cur][a]);
#pragma unroll
                for (int g = 0; g < 4; ++g)
                    acc[a][g] = __builtin_amdgcn_mfma_f32_16x16x32_bf16(af, bfr[g], acc[a][g], 0, 0, 0);
            }
        }
        __syncthreads();
    }

    // epilogue: out[n][oc][oy][ox] = lrelu(acc+b2) + up2(t2)*RSQRT2  (pure store)
    const int oy = oy0 + w;
    int ry0, ry1; float wy0, wy1;
    up2_coef(oy, 63, ry0, ry1, wy0, wy1);
    const unsigned short* t2b = t2 + ((size_t)n << 19);      // n*4096*128
#pragma unroll
    for (int a = 0; a < 4; ++a) {
        const int oc = oc0 + (a << 4) + (q << 2);
        float bb[4] = {b2[oc], b2[oc + 1], b2[oc + 2], b2[oc + 3]};
        float* pbase = out + ((size_t)(((n << 7) + oc) << 7) + oy) * 128;
#pragma unroll
        for (int g = 0; g < 4; ++g) {
            const int ox = x0 + (g << 4) + m;
            int cx0, cx1; float wx0, wx1;
            up2_coef(ox, 63, cx0, cx1, wx0, wx1);
            uint2 A = *(const uint2*)(t2b + (((ry0 << 6) + cx0) << 7) + oc);
            uint2 B = *(const uint2*)(t2b + (((ry0 << 6) + cx1) << 7) + oc);
            uint2 C = *(const uint2*)(t2b + (((ry1 << 6) + cx0) << 7) + oc);
            uint2 D = *(const uint2*)(t2b + (((ry1 << 6) + cx1) << 7) + oc);
            const unsigned* pA = (const unsigned*)&A; const unsigned* pB = (const unsigned*)&B;
            const unsigned* pC = (const unsigned*)&C; const unsigned* pD = (const unsigned*)&D;
#pragma unroll
            for (int r = 0; r < 4; ++r) {
                unsigned wa = pA[r >> 1], wb = pB[r >> 1], wc = pC[r >> 1], wd = pD[r >> 1];
                float va = (r & 1) ? bfhi(wa) : bflo(wa);
                float vb = (r & 1) ? bfhi(wb) : bflo(wb);
                float vc = (r & 1) ? bfhi(wc) : bflo(wc);
                float vd = (r & 1) ? bfhi(wd) : bflo(wd);
                float sk = wy0 * (wx0 * va + wx1 * vb) + wy1 * (wx0 * vc + wx1 * vd);
                pbase[(size_t)r * 16384 + ox] = lrelu_s(acc[a][g][r] + bb[r]) + sk * RSQRT2F;
            }
        }
    }
}

// ---------------------------------------------------------------------------
// Fallback path (used only if workspace too small for u): old upskip + conv2
// ---------------------------------------------------------------------------
__global__ __launch_bounds__(256) void k_upskip(
    const unsigned short* __restrict__ t2, float* __restrict__ out)
{
    const int tid = threadIdx.x;
    const int oc8 = tid & 15, oxi = tid >> 4;
    const int ox = (blockIdx.x << 4) + oxi;
    const int oy = blockIdx.y;
    const int n  = blockIdx.z;

    int ry0, ry1, cx0, cx1; float wy0, wy1, wx0, wx1;
    up2_coef(oy, 63, ry0, ry1, wy0, wy1);
    up2_coef(ox, 63, cx0, cx1, wx0, wx1);

    const unsigned short* base = t2 + ((size_t)n << 19);
    const int co = oc8 << 3;
    uint4 v00 = *(const uint4*)(base + (((ry0 << 6) + cx0) << 7) + co);
    uint4 v01 = *(const uint4*)(base + (((ry0 << 6) + cx1) << 7) + co);
    uint4 v10 = *(const uint4*)(base + (((ry1 << 6) + cx0) << 7) + co);
    uint4 v11 = *(const uint4*)(base + (((ry1 << 6) + cx1) << 7) + co);
    const unsigned* pa = (const unsigned*)&v00; const unsigned* pb = (const unsigned*)&v01;
    const unsigned* pc = (const unsigned*)&v10; const unsigned* pd = (const unsigned*)&v11;

    float* o = out + ((size_t)(((n << 7) + co) << 7) + oy) * 128 + ox;
#pragma unroll
    for (int j = 0; j < 4; ++j) {
        float vlo = wy0 * (wx0 * bflo(pa[j]) + wx1 * bflo(pb[j]))
                  + wy1 * (wx0 * bflo(pc[j]) + wx1 * bflo(pd[j]));
        float vhi = wy0 * (wx0 * bfhi(pa[j]) + wx1 * bfhi(pb[j]))
                  + wy1 * (wx0 * bfhi(pc[j]) + wx1 * bfhi(pd[j]));
        o[(size_t)(2 * j) * 16384]     = vlo * RSQRT2F;
        o[(size_t)(2 * j + 1) * 16384] = vhi * RSQRT2F;
    }
}

__global__ __launch_bounds__(256, 2) void k_conv2(
    const unsigned short* __restrict__ t1, const unsigned short* __restrict__ w2T,
    const float* __restrict__ b2, float* __restrict__ out)
{
    __shared__ __align__(16) unsigned short ut[4][130][40];  // 41.6 KB
    const int tid  = threadIdx.x;
    const int n    = blockIdx.x >> 6;
    const int oy0  = (blockIdx.x & 63) << 1;
    const int oc0  = blockIdx.y << 6;
    const int w    = tid >> 6;
    const int m    = tid & 15;
    const int q    = (tid & 63) >> 4;
    const int wrow = w >> 1;
    const int wxh  = (w & 1) << 6;

    f32x4 acc[4][4];
#pragma unroll
    for (int a = 0; a < 4; ++a)
#pragma unroll
        for (int g = 0; g < 4; ++g) acc[a][g] = (f32x4){0.f, 0.f, 0.f, 0.f};

    const unsigned short* wbase = w2T + (oc0 + m) * 2304 + (q << 3);
    const unsigned short* tb    = t1 + ((size_t)n << 20);

    for (int c0 = 0; c0 < 256; c0 += 32) {
        for (int idx = tid; idx < 2080; idx += 256) {
            int r = idx / 520; int rem = idx - r * 520; int col = rem >> 2; int g = rem & 3;
            int oy = oy0 - 1 + r, ox = col - 1;
            uint4 res = make_uint4(0, 0, 0, 0);
            if ((unsigned)oy < 128u && (unsigned)ox < 128u) {
                int ry0, ry1, cx0, cx1; float wy0, wy1, wx0, wx1;
                up2_coef(oy, 63, ry0, ry1, wy0, wy1);
                up2_coef(ox, 63, cx0, cx1, wx0, wx1);
                const int co = c0 + (g << 3);
                uint4 v00 = *(const uint4*)(tb + (((ry0 << 6) + cx0) << 8) + co);
                uint4 v01 = *(const uint4*)(tb + (((ry0 << 6) + cx1) << 8) + co);
                uint4 v10 = *(const uint4*)(tb + (((ry1 << 6) + cx0) << 8) + co);
                uint4 v11 = *(const uint4*)(tb + (((ry1 << 6) + cx1) << 8) + co);
                const unsigned* pa = (const unsigned*)&v00; const unsigned* pb = (const unsigned*)&v01;
                const unsigned* pc = (const unsigned*)&v10; const unsigned* pd = (const unsigned*)&v11;
                unsigned* pr = (unsigned*)&res;
#pragma unroll
                for (int j = 0; j < 4; ++j) {
                    float vlo = wy0 * (wx0 * bflo(pa[j]) + wx1 * bflo(pb[j]))
                              + wy1 * (wx0 * bflo(pc[j]) + wx1 * bflo(pd[j]));
                    float vhi = wy0 * (wx0 * bfhi(pa[j]) + wx1 * bfhi(pb[j]))
                              + wy1 * (wx0 * bfhi(pc[j]) + wx1 * bfhi(pd[j]));
                    pr[j] = (unsigned)f2bf(vlo) | ((unsigned)f2bf(vhi) << 16);
                }
            }
            *(uint4*)(&ut[r][col][g << 3]) = res;
        }
        __syncthreads();

        uint4 aq[2][4];
#pragma unroll
        for (int a = 0; a < 4; ++a)
            aq[0][a] = *(const uint4*)(wbase + a * (16 * 2304) + c0);
#pragma unroll
        for (int tap = 0; tap < 9; ++tap) {
            const int cur = tap & 1;
            if (tap < 8) {
#pragma unroll
                for (int a = 0; a < 4; ++a)
                    aq[cur ^ 1][a] = *(const uint4*)(wbase + a * (16 * 2304) + (tap + 1) * 256 + c0);
            }
            const int dy = tap / 3, dx = tap - 3 * (tap / 3);
            bf16x8 bfr[4];
#pragma unroll
            for (int g = 0; g < 4; ++g)
                bfr[g] = *(const bf16x8*)(&ut[wrow + dy][wxh + (g << 4) + m + dx][q << 3]);
#pragma unroll
            for (int a = 0; a < 4; ++a) {
                bf16x8 af = __builtin_bit_cast(bf16x8, aq[cur][a]);
#pragma unroll
                for (int g = 0; g < 4; ++g)
                    acc[a][g] = __builtin_amdgcn_mfma_f32_16x16x32_bf16(af, bfr[g], acc[a][g], 0, 0, 0);
            }
        }
        __syncthreads();
    }

    const int oy = oy0 + wrow;
#pragma unroll
    for (int a = 0; a < 4; ++a) {
        const int oc = oc0 + (a << 4) + (q << 2);
        float bb[4] = {b2[oc], b2[oc + 1], b2[oc + 2], b2[oc + 3]};
#pragma unroll
        for (int g = 0; g < 4; ++g) {
            const int ox = wxh + (g << 4) + m;
            float* p = out + (size_t)((((n << 7) + oc) << 7) + oy) * 128 + ox;
#pragma unroll
            for (int r = 0; r < 4; ++r)
                p[(size_t)r * 16384] += lrelu_s(acc[a][g][r] + bb[r]);
        }
    }
}

// ---------------------------------------------------------------------------
extern "C" void kernel_launch(void* const* d_in, const int* in_sizes, int n_in,
                              void* d_out, int out_size, void* d_ws, size_t ws_size,
                              hipStream_t stream)
{
    const float* x   = (const float*)d_in[0];
    const float* w1  = (const float*)d_in[1];
    const float* b1  = (const float*)d_in[2];
    const float* w2  = (const float*)d_in[3];
    const float* b2  = (const float*)d_in[4];
    const float* wsk = (const float*)d_in[5];
    float* out = (float*)d_out;

    unsigned short* xT  = (unsigned short*)d_ws;        // 8,388,608 elems
    unsigned short* t1  = xT + 8388608;                 // 8,388,608
    unsigned short* t2  = t1 + 8388608;                 // 4,194,304
    unsigned short* w1T = t2 + 4194304;                 // 589,824
    unsigned short* w2T = w1T + 589824;                 // 294,912
    unsigned short* wsT = w2T + 294912;                 // 32,768
    unsigned short* u   = wsT + 32768;                  // 33,554,432 (u-path only)
    const size_t need_u = (size_t)(8388608 + 8388608 + 4194304 + 589824 + 294912 + 32768
                                   + 33554432) * 2;     // ~110.9 MB

    k_wt3   <<<dim3(2304), 256, 0, stream>>>(w1, w1T, 589824, 1.0f / 48.0f);
    k_wt3   <<<dim3(1152), 256, 0, stream>>>(w2, w2T, 294912, 1.0f / 48.0f);
    k_wt1   <<<dim3(128),  256, 0, stream>>>(wsk, wsT, 32768, 1.0f / 16.0f);
    k_xprep <<<dim3(64, 4, 8), 256, 0, stream>>>(x, xT);
    k_conv1 <<<dim3(128, 4), 256, 0, stream>>>(xT, w1T, b1, t1);
    k_skip  <<<dim3(512), 256, 0, stream>>>(xT, wsT, t2);

    if (ws_size >= need_u) {
        k_synthu <<<dim3(2, 128, 8), 256, 0, stream>>>(t1, u);
        k_conv2u <<<dim3(512, 2), 256, 0, stream>>>(u, w2T, t2, b2, out);
    } else {
        k_upskip <<<dim3(8, 128, 8), 256, 0, stream>>>(t2, out);
        k_conv2  <<<dim3(512, 2), 256, 0, stream>>>(t1, w2T, b2, out);
    }
}

// Round 3
// 409.125 us; speedup vs baseline: 1.2316x; 1.2316x over previous
//
#include <hip/hip_runtime.h>
#include <hip/hip_bf16.h>

// ResUpBlock via bf16 MFMA implicit GEMM (fp32 accumulate).
//   xT  = channels-last bf16 copy of x              [8][64][64][256]
//   t1  = lrelu(conv3x3(x,w1/48)+b1)*sqrt2 -> bf16  [8][64][64][256] (channels-last)
//   t2  = conv1x1(x, wsk/16)              -> bf16   [8][64][64][128] (channels-last)
//   u   = upsample2x(t1)                  -> bf16   [8][128][128][256] (k_synthu)
//   out = lrelu(conv3x3(u,w2/48)+b2) + up2(t2)/sqrt2  (k_conv2u, skip fused in epilogue)
// conv1/conv2u K-loop uses T14 async-STAGE split: per-thread staging offsets are
// precomputed; chunk c+1's global loads are issued BEFORE the barrier ahead of chunk
// c's MFMA phase, so ~900cy HBM latency hides under ~700cy of MFMA + barrier.
// mfma_f32_16x16x32_bf16: A/B frag = 8 contiguous k per lane, C/D col=lane&15,
// row=quad*4+reg (verified per guide m89/m120).

typedef __attribute__((ext_vector_type(8))) short bf16x8;
typedef __attribute__((ext_vector_type(4))) float f32x4;

#define SQRT2F  1.41421356237309504880f
#define RSQRT2F 0.70710678118654752440f

__device__ __forceinline__ float lrelu_s(float v) { return v >= 0.f ? v : 0.2f * v; }

__device__ __forceinline__ unsigned short f2bf(float f) {
    unsigned u = __builtin_bit_cast(unsigned, f);
    u += 0x7fffu + ((u >> 16) & 1u);          // RNE
    return (unsigned short)(u >> 16);
}
__device__ __forceinline__ float bflo(unsigned u) {
    return __builtin_bit_cast(float, u << 16);
}
__device__ __forceinline__ float bfhi(unsigned u) {
    return __builtin_bit_cast(float, u & 0xffff0000u);
}

// bilinear 2x coefficients (align_corners=False, matches jax.image.resize; edge-clamped)
__device__ __forceinline__ void up2_coef(int o, int lim, int& i0, int& i1, float& w0, float& w1) {
    int h = o >> 1;
    if (o & 1) { i0 = h; i1 = (h + 1 > lim) ? lim : h + 1; w0 = 0.75f; w1 = 0.25f; }
    else       { i0 = (h - 1 < 0) ? 0 : h - 1; i1 = h;     w0 = 0.25f; w1 = 0.75f; }
}

// ---------------------------------------------------------------------------
// weight transforms
// ---------------------------------------------------------------------------
__global__ __launch_bounds__(256) void k_wt3(const float* __restrict__ w,
                                             unsigned short* __restrict__ wt,
                                             int total, float scale) {
    int i = blockIdx.x * 256 + threadIdx.x;           // i over OC*9*256, layout [oc][tap][c]
    if (i >= total) return;
    int c = i & 255; int rem = i >> 8; int tap = rem % 9; int oc = rem / 9;
    wt[i] = f2bf(w[(oc * 256 + c) * 9 + tap] * scale);
}

__global__ __launch_bounds__(256) void k_wt1(const float* __restrict__ w,
                                             unsigned short* __restrict__ wt,
                                             int total, float scale) {
    int i = blockIdx.x * 256 + threadIdx.x;           // [oc][c] identity layout
    if (i >= total) return;
    wt[i] = f2bf(w[i] * scale);
}

// ---------------------------------------------------------------------------
// x (NCHW f32) -> xT (channels-last bf16) via LDS transpose
// ---------------------------------------------------------------------------
__global__ __launch_bounds__(256) void k_xprep(const float* __restrict__ x,
                                               unsigned short* __restrict__ xT) {
    __shared__ float t[64][65];
    const int n = blockIdx.z, c0 = blockIdx.y << 6, p0 = blockIdx.x << 6;
    for (int i = threadIdx.x; i < 4096; i += 256) {
        int c = i >> 6, p = i & 63;
        t[c][p] = x[((size_t)(n * 256 + c0 + c) << 12) + p0 + p];
    }
    __syncthreads();
    for (int i = threadIdx.x; i < 4096; i += 256) {
        int p = i >> 6, c = i & 63;
        xT[((size_t)((n << 12) + p0 + p) << 8) + c0 + c] = f2bf(t[c][p]);
    }
}

// ---------------------------------------------------------------------------
// conv1: t1 = lrelu(conv3x3(x)+b1)*sqrt2, bf16 channels-last. T14-pipelined.
// block: M=64 oc x N=256 px (4 rows x 64 cols); grid dim3(128, 4)
// ---------------------------------------------------------------------------
__global__ __launch_bounds__(256, 2) void k_conv1(
    const unsigned short* __restrict__ xT, const unsigned short* __restrict__ w1T,
    const float* __restrict__ b1, unsigned short* __restrict__ t1)
{
    __shared__ __align__(16) unsigned short dt[6][66][40];   // 31.7 KB, c padded 32->40
    const int tid = threadIdx.x;
    const int n   = blockIdx.x >> 4;
    const int y0  = (blockIdx.x & 15) << 2;
    const int oc0 = blockIdx.y << 6;
    const int w   = tid >> 6;
    const int m   = tid & 15;
    const int q   = (tid & 63) >> 4;

    f32x4 acc[4][4];
#pragma unroll
    for (int a = 0; a < 4; ++a)
#pragma unroll
        for (int g = 0; g < 4; ++g) acc[a][g] = (f32x4){0.f, 0.f, 0.f, 0.f};

    const unsigned short* wbase = w1T + (oc0 + m) * 2304 + (q << 3);
    const unsigned short* xTn   = xT + ((size_t)n << 20);    // n*4096*256
    unsigned short* dtf = &dt[0][0][0];

    // precompute per-thread staging slots: 1584 uint4 = rows 0..5 x cols 0..65 x g 0..3
    int goff[7], ldsoff[7];
#pragma unroll
    for (int k = 0; k < 7; ++k) {
        int idx = tid + (k << 8);
        goff[k] = -1; ldsoff[k] = -1;
        if (idx < 1584) {
            int r = idx / 264; int rem = idx - r * 264; int col = rem >> 2; int g = rem & 3;
            ldsoff[k] = (r * 66 + col) * 40 + (g << 3);
            int gy = y0 - 1 + r, gx = col - 1;
            if ((unsigned)gy < 64u && (unsigned)gx < 64u)
                goff[k] = (((gy << 6) + gx) << 8) + (g << 3);
        }
    }

    // prologue: zero + issue chunk0 loads (OOB lanes stay zero forever)
    uint4 vreg[7];
#pragma unroll
    for (int k = 0; k < 7; ++k) {
        vreg[k] = make_uint4(0, 0, 0, 0);
        if (goff[k] >= 0) vreg[k] = *(const uint4*)(xTn + goff[k]);
    }

    for (int ci = 0; ci < 8; ++ci) {
        const int c0 = ci << 5;
        // drain chunk ci into LDS (one waitcnt for all loads)
#pragma unroll
        for (int k = 0; k < 7; ++k)
            if (ldsoff[k] >= 0) *(uint4*)(dtf + ldsoff[k]) = vreg[k];
        // issue chunk ci+1 loads: in flight across barrier + MFMA phase
        if (ci < 7) {
            const int cn = (ci + 1) << 5;
#pragma unroll
            for (int k = 0; k < 7; ++k)
                if (goff[k] >= 0) vreg[k] = *(const uint4*)(xTn + goff[k] + cn);
        }
        __syncthreads();

        uint4 aq[2][4];
#pragma unroll
        for (int a = 0; a < 4; ++a)
            aq[0][a] = *(const uint4*)(wbase + a * (16 * 2304) + c0);   // tap 0
#pragma unroll
        for (int tap = 0; tap < 9; ++tap) {
            const int cur = tap & 1;
            if (tap < 8) {
#pragma unroll
                for (int a = 0; a < 4; ++a)
                    aq[cur ^ 1][a] = *(const uint4*)(wbase + a * (16 * 2304) + (tap + 1) * 256 + c0);
            }
            const int dy = tap / 3, dx = tap - 3 * (tap / 3);
            bf16x8 bfr[4];
#pragma unroll
            for (int g = 0; g < 4; ++g)
                bfr[g] = *(const bf16x8*)(&dt[w + dy][(g << 4) + m + dx][q << 3]);
#pragma unroll
            for (int a = 0; a < 4; ++a) {
                bf16x8 af = __builtin_bit_cast(bf16x8, aq[cur][a]);
#pragma unroll
                for (int g = 0; g < 4; ++g)
                    acc[a][g] = __builtin_amdgcn_mfma_f32_16x16x32_bf16(af, bfr[g], acc[a][g], 0, 0, 0);
            }
        }
        __syncthreads();
    }

    // epilogue: lane holds 4 consecutive oc (q*4+r) at px (g*16+m) -> 8B bf16 stores
    const int y = y0 + w;
#pragma unroll
    for (int a = 0; a < 4; ++a) {
        const int oc = oc0 + (a << 4) + (q << 2);
        float b0 = b1[oc], b1v = b1[oc + 1], b2v = b1[oc + 2], b3 = b1[oc + 3];
#pragma unroll
        for (int g = 0; g < 4; ++g) {
            const int xcol = (g << 4) + m;
            unsigned lo = (unsigned)f2bf(lrelu_s(acc[a][g][0] + b0) * SQRT2F)
                        | ((unsigned)f2bf(lrelu_s(acc[a][g][1] + b1v) * SQRT2F) << 16);
            unsigned hi = (unsigned)f2bf(lrelu_s(acc[a][g][2] + b2v) * SQRT2F)
                        | ((unsigned)f2bf(lrelu_s(acc[a][g][3] + b3) * SQRT2F) << 16);
            uint2 s; s.x = lo; s.y = hi;
            *(uint2*)(t1 + (((n << 12) + (y << 6) + xcol) << 8) + oc) = s;
        }
    }
}

// ---------------------------------------------------------------------------
// skip GEMM: t2[px][oc] = sum_c xT[px][c]*wsT[oc][c]
// ---------------------------------------------------------------------------
__global__ __launch_bounds__(256, 2) void k_skip(
    const unsigned short* __restrict__ xT, const unsigned short* __restrict__ wsT,
    unsigned short* __restrict__ t2)
{
    const int tid = threadIdx.x;
    const int w = tid >> 6, m = tid & 15, q = (tid & 63) >> 4;
    const int px0 = blockIdx.x << 6;
    const int apx = px0 + (w << 4) + m;

    f32x4 acc[8];
#pragma unroll
    for (int g = 0; g < 8; ++g) acc[g] = (f32x4){0.f, 0.f, 0.f, 0.f};

#pragma unroll
    for (int c0 = 0; c0 < 256; c0 += 32) {
        bf16x8 af = *(const bf16x8*)(xT + ((size_t)apx << 8) + c0 + (q << 3));
#pragma unroll
        for (int g = 0; g < 8; ++g) {
            bf16x8 bf = *(const bf16x8*)(wsT + (((g << 4) + m) << 8) + c0 + (q << 3));
            acc[g] = __builtin_amdgcn_mfma_f32_16x16x32_bf16(af, bf, acc[g], 0, 0, 0);
        }
    }
#pragma unroll
    for (int g = 0; g < 8; ++g) {
        const int oc = (g << 4) + m;
#pragma unroll
        for (int r = 0; r < 4; ++r) {
            int opx = px0 + (w << 4) + (q << 2) + r;
            t2[((size_t)opx << 7) + oc] = f2bf(acc[g][r]);
        }
    }
}

// ---------------------------------------------------------------------------
// k_synthu: u[n][oy][ox][c] = bilinear2x(t1), bf16 channels-last.
// grid dim3(2, 128, 8)
// ---------------------------------------------------------------------------
__global__ __launch_bounds__(256) void k_synthu(
    const unsigned short* __restrict__ t1, unsigned short* __restrict__ u)
{
    const int n = blockIdx.z, oy = blockIdx.y, x0 = blockIdx.x << 6;
    int ry0, ry1; float wy0, wy1;
    up2_coef(oy, 63, ry0, ry1, wy0, wy1);
    const unsigned short* tb = t1 + ((size_t)n << 20);           // n*4096*256
    unsigned short* ub = u + ((size_t)((n << 7) + oy) << 15);    // row = 128*256 elems

    for (int idx = threadIdx.x; idx < 2048; idx += 256) {
        const int ox = x0 + (idx >> 5), g = idx & 31;
        int cx0, cx1; float wx0, wx1;
        up2_coef(ox, 63, cx0, cx1, wx0, wx1);
        const int co = g << 3;
        uint4 v00 = *(const uint4*)(tb + (((ry0 << 6) + cx0) << 8) + co);
        uint4 v01 = *(const uint4*)(tb + (((ry0 << 6) + cx1) << 8) + co);
        uint4 v10 = *(const uint4*)(tb + (((ry1 << 6) + cx0) << 8) + co);
        uint4 v11 = *(const uint4*)(tb + (((ry1 << 6) + cx1) << 8) + co);
        const unsigned* pa = (const unsigned*)&v00; const unsigned* pb = (const unsigned*)&v01;
        const unsigned* pc = (const unsigned*)&v10; const unsigned* pd = (const unsigned*)&v11;
        uint4 res; unsigned* pr = (unsigned*)&res;
#pragma unroll
        for (int j = 0; j < 4; ++j) {
            float vlo = wy0 * (wx0 * bflo(pa[j]) + wx1 * bflo(pb[j]))
                      + wy1 * (wx0 * bflo(pc[j]) + wx1 * bflo(pd[j]));
            float vhi = wy0 * (wx0 * bfhi(pa[j]) + wx1 * bfhi(pb[j]))
                      + wy1 * (wx0 * bfhi(pc[j]) + wx1 * bfhi(pd[j]));
            pr[j] = (unsigned)f2bf(vlo) | ((unsigned)f2bf(vhi) << 16);
        }
        *(uint4*)(ub + (ox << 8) + co) = res;
    }
}

// ---------------------------------------------------------------------------
// k_conv2u: out = lrelu(conv3x3(u)+b2) + up2(t2)*RSQRT2. T14-pipelined staging.
// block: M=64 oc x N=256 px (4 oy rows x 64 ox cols); grid dim3(512, 2)
// ---------------------------------------------------------------------------
__global__ __launch_bounds__(256, 2) void k_conv2u(
    const unsigned short* __restrict__ u, const unsigned short* __restrict__ w2T,
    const unsigned short* __restrict__ t2, const float* __restrict__ b2,
    float* __restrict__ out)
{
    __shared__ __align__(16) unsigned short dt[6][66][40];   // 31.7 KB
    const int tid  = threadIdx.x;
    const int n    = blockIdx.x >> 6;
    const int rest = blockIdx.x & 63;
    const int oy0  = (rest >> 1) << 2;
    const int x0   = (rest & 1) << 6;
    const int oc0  = blockIdx.y << 6;
    const int w    = tid >> 6;
    const int m    = tid & 15;
    const int q    = (tid & 63) >> 4;

    f32x4 acc[4][4];
#pragma unroll
    for (int a = 0; a < 4; ++a)
#pragma unroll
        for (int g = 0; g < 4; ++g) acc[a][g] = (f32x4){0.f, 0.f, 0.f, 0.f};

    const unsigned short* wbase = w2T + (oc0 + m) * 2304 + (q << 3);
    const unsigned short* ub    = u + ((size_t)n << 22);     // n*16384*256
    unsigned short* dtf = &dt[0][0][0];

    // precompute staging slots: rows oy0-1..oy0+4, cols x0-1..x0+64, 4 c-groups
    int goff[7], ldsoff[7];
#pragma unroll
    for (int k = 0; k < 7; ++k) {
        int idx = tid + (k << 8);
        goff[k] = -1; ldsoff[k] = -1;
        if (idx < 1584) {
            int r = idx / 264; int rem = idx - r * 264; int col = rem >> 2; int g = rem & 3;
            ldsoff[k] = (r * 66 + col) * 40 + (g << 3);
            int gy = oy0 - 1 + r, gx = x0 - 1 + col;
            if ((unsigned)gy < 128u && (unsigned)gx < 128u)
                goff[k] = (((gy << 7) + gx) << 8) + (g << 3);
        }
    }

    uint4 vreg[7];
#pragma unroll
    for (int k = 0; k < 7; ++k) {
        vreg[k] = make_uint4(0, 0, 0, 0);
        if (goff[k] >= 0) vreg[k] = *(const uint4*)(ub + goff[k]);
    }

    for (int ci = 0; ci < 8; ++ci) {
        const int c0 = ci << 5;
#pragma unroll
        for (int k = 0; k < 7; ++k)
            if (ldsoff[k] >= 0) *(uint4*)(dtf + ldsoff[k]) = vreg[k];
        if (ci < 7) {
            const int cn = (ci + 1) << 5;
#pragma unroll
            for (int k = 0; k < 7; ++k)
                if (goff[k] >= 0) vreg[k] = *(const uint4*)(ub + goff[k] + cn);
        }
        __syncthreads();

        uint4 aq[2][4];
#pragma unroll
        for (int a = 0; a < 4; ++a)
            aq[0][a] = *(const uint4*)(wbase + a * (16 * 2304) + c0);
#pragma unroll
        for (int tap = 0; tap < 9; ++tap) {
            const int cur = tap & 1;
            if (tap < 8) {
#pragma unroll
                for (int a = 0; a < 4; ++a)
                    aq[cur ^ 1][a] = *(const uint4*)(wbase + a * (16 * 2304) + (tap + 1) * 256 + c0);
            }
            const int dy = tap / 3, dx = tap - 3 * (tap / 3);
            bf16x8 bfr[4];
#pragma unroll
            for (int g = 0; g < 4; ++g)
                bfr[g] = *(const bf16x8*)(&dt[w + dy][(g << 4) + m + dx][q << 3]);
#pragma unroll
            for (int a = 0; a < 4; ++a) {
                bf16x8 af = __builtin_bit_cast(bf16x8, aq[cur][a]);
#pragma unroll
                for (int g = 0; g < 4; ++g)
                    acc[a][g] = __builtin_amdgcn_mfma_f32_16x16x32_bf16(af, bfr[g], acc[a][g], 0, 0, 0);
            }
        }
        __syncthreads();
    }

    // epilogue: out[n][oc][oy][ox] = lrelu(acc+b2) + up2(t2)*RSQRT2  (pure store)
    const int oy = oy0 + w;
    int ry0, ry1; float wy0, wy1;
    up2_coef(oy, 63, ry0, ry1, wy0, wy1);
    const unsigned short* t2b = t2 + ((size_t)n << 19);      // n*4096*128
#pragma unroll
    for (int a = 0; a < 4; ++a) {
        const int oc = oc0 + (a << 4) + (q << 2);
        float bb[4] = {b2[oc], b2[oc + 1], b2[oc + 2], b2[oc + 3]};
        float* pbase = out + ((size_t)(((n << 7) + oc) << 7) + oy) * 128;
#pragma unroll
        for (int g = 0; g < 4; ++g) {
            const int ox = x0 + (g << 4) + m;
            int cx0, cx1; float wx0, wx1;
            up2_coef(ox, 63, cx0, cx1, wx0, wx1);
            uint2 A = *(const uint2*)(t2b + (((ry0 << 6) + cx0) << 7) + oc);
            uint2 B = *(const uint2*)(t2b + (((ry0 << 6) + cx1) << 7) + oc);
            uint2 C = *(const uint2*)(t2b + (((ry1 << 6) + cx0) << 7) + oc);
            uint2 D = *(const uint2*)(t2b + (((ry1 << 6) + cx1) << 7) + oc);
            const unsigned* pA = (const unsigned*)&A; const unsigned* pB = (const unsigned*)&B;
            const unsigned* pC = (const unsigned*)&C; const unsigned* pD = (const unsigned*)&D;
#pragma unroll
            for (int r = 0; r < 4; ++r) {
                unsigned wa = pA[r >> 1], wb = pB[r >> 1], wc = pC[r >> 1], wd = pD[r >> 1];
                float va = (r & 1) ? bfhi(wa) : bflo(wa);
                float vb = (r & 1) ? bfhi(wb) : bflo(wb);
                float vc = (r & 1) ? bfhi(wc) : bflo(wc);
                float vd = (r & 1) ? bfhi(wd) : bflo(wd);
                float sk = wy0 * (wx0 * va + wx1 * vb) + wy1 * (wx0 * vc + wx1 * vd);
                pbase[(size_t)r * 16384 + ox] = lrelu_s(acc[a][g][r] + bb[r]) + sk * RSQRT2F;
            }
        }
    }
}

// ---------------------------------------------------------------------------
// Fallback path (used only if workspace too small for u): old upskip + conv2
// ---------------------------------------------------------------------------
__global__ __launch_bounds__(256) void k_upskip(
    const unsigned short* __restrict__ t2, float* __restrict__ out)
{
    const int tid = threadIdx.x;
    const int oc8 = tid & 15, oxi = tid >> 4;
    const int ox = (blockIdx.x << 4) + oxi;
    const int oy = blockIdx.y;
    const int n  = blockIdx.z;

    int ry0, ry1, cx0, cx1; float wy0, wy1, wx0, wx1;
    up2_coef(oy, 63, ry0, ry1, wy0, wy1);
    up2_coef(ox, 63, cx0, cx1, wx0, wx1);

    const unsigned short* base = t2 + ((size_t)n << 19);
    const int co = oc8 << 3;
    uint4 v00 = *(const uint4*)(base + (((ry0 << 6) + cx0) << 7) + co);
    uint4 v01 = *(const uint4*)(base + (((ry0 << 6) + cx1) << 7) + co);
    uint4 v10 = *(const uint4*)(base + (((ry1 << 6) + cx0) << 7) + co);
    uint4 v11 = *(const uint4*)(base + (((ry1 << 6) + cx1) << 7) + co);
    const unsigned* pa = (const unsigned*)&v00; const unsigned* pb = (const unsigned*)&v01;
    const unsigned* pc = (const unsigned*)&v10; const unsigned* pd = (const unsigned*)&v11;

    float* o = out + ((size_t)(((n << 7) + co) << 7) + oy) * 128 + ox;
#pragma unroll
    for (int j = 0; j < 4; ++j) {
        float vlo = wy0 * (wx0 * bflo(pa[j]) + wx1 * bflo(pb[j]))
                  + wy1 * (wx0 * bflo(pc[j]) + wx1 * bflo(pd[j]));
        float vhi = wy0 * (wx0 * bfhi(pa[j]) + wx1 * bfhi(pb[j]))
                  + wy1 * (wx0 * bfhi(pc[j]) + wx1 * bfhi(pd[j]));
        o[(size_t)(2 * j) * 16384]     = vlo * RSQRT2F;
        o[(size_t)(2 * j + 1) * 16384] = vhi * RSQRT2F;
    }
}

__global__ __launch_bounds__(256, 2) void k_conv2(
    const unsigned short* __restrict__ t1, const unsigned short* __restrict__ w2T,
    const float* __restrict__ b2, float* __restrict__ out)
{
    __shared__ __align__(16) unsigned short ut[4][130][40];  // 41.6 KB
    const int tid  = threadIdx.x;
    const int n    = blockIdx.x >> 6;
    const int oy0  = (blockIdx.x & 63) << 1;
    const int oc0  = blockIdx.y << 6;
    const int w    = tid >> 6;
    const int m    = tid & 15;
    const int q    = (tid & 63) >> 4;
    const int wrow = w >> 1;
    const int wxh  = (w & 1) << 6;

    f32x4 acc[4][4];
#pragma unroll
    for (int a = 0; a < 4; ++a)
#pragma unroll
        for (int g = 0; g < 4; ++g) acc[a][g] = (f32x4){0.f, 0.f, 0.f, 0.f};

    const unsigned short* wbase = w2T + (oc0 + m) * 2304 + (q << 3);
    const unsigned short* tb    = t1 + ((size_t)n << 20);

    for (int c0 = 0; c0 < 256; c0 += 32) {
        for (int idx = tid; idx < 2080; idx += 256) {
            int r = idx / 520; int rem = idx - r * 520; int col = rem >> 2; int g = rem & 3;
            int oy = oy0 - 1 + r, ox = col - 1;
            uint4 res = make_uint4(0, 0, 0, 0);
            if ((unsigned)oy < 128u && (unsigned)ox < 128u) {
                int ry0, ry1, cx0, cx1; float wy0, wy1, wx0, wx1;
                up2_coef(oy, 63, ry0, ry1, wy0, wy1);
                up2_coef(ox, 63, cx0, cx1, wx0, wx1);
                const int co = c0 + (g << 3);
                uint4 v00 = *(const uint4*)(tb + (((ry0 << 6) + cx0) << 8) + co);
                uint4 v01 = *(const uint4*)(tb + (((ry0 << 6) + cx1) << 8) + co);
                uint4 v10 = *(const uint4*)(tb + (((ry1 << 6) + cx0) << 8) + co);
                uint4 v11 = *(const uint4*)(tb + (((ry1 << 6) + cx1) << 8) + co);
                const unsigned* pa = (const unsigned*)&v00; const unsigned* pb = (const unsigned*)&v01;
                const unsigned* pc = (const unsigned*)&v10; const unsigned* pd = (const unsigned*)&v11;
                unsigned* pr = (unsigned*)&res;
#pragma unroll
                for (int j = 0; j < 4; ++j) {
                    float vlo = wy0 * (wx0 * bflo(pa[j]) + wx1 * bflo(pb[j]))
                              + wy1 * (wx0 * bflo(pc[j]) + wx1 * bflo(pd[j]));
                    float vhi = wy0 * (wx0 * bfhi(pa[j]) + wx1 * bfhi(pb[j]))
                              + wy1 * (wx0 * bfhi(pc[j]) + wx1 * bfhi(pd[j]));
                    pr[j] = (unsigned)f2bf(vlo) | ((unsigned)f2bf(vhi) << 16);
                }
            }
            *(uint4*)(&ut[r][col][g << 3]) = res;
        }
        __syncthreads();

        uint4 aq[2][4];
#pragma unroll
        for (int a = 0; a < 4; ++a)
            aq[0][a] = *(const uint4*)(wbase + a * (16 * 2304) + c0);
#pragma unroll
        for (int tap = 0; tap < 9; ++tap) {
            const int cur = tap & 1;
            if (tap < 8) {
#pragma unroll
                for (int a = 0; a < 4; ++a)
                    aq[cur ^ 1][a] = *(const uint4*)(wbase + a * (16 * 2304) + (tap + 1) * 256 + c0);
            }
            const int dy = tap / 3, dx = tap - 3 * (tap / 3);
            bf16x8 bfr[4];
#pragma unroll
            for (int g = 0; g < 4; ++g)
                bfr[g] = *(const bf16x8*)(&ut[wrow + dy][wxh + (g << 4) + m + dx][q << 3]);
#pragma unroll
            for (int a = 0; a < 4; ++a) {
                bf16x8 af = __builtin_bit_cast(bf16x8, aq[cur][a]);
#pragma unroll
                for (int g = 0; g < 4; ++g)
                    acc[a][g] = __builtin_amdgcn_mfma_f32_16x16x32_bf16(af, bfr[g], acc[a][g], 0, 0, 0);
            }
        }
        __syncthreads();
    }

    const int oy = oy0 + wrow;
#pragma unroll
    for (int a = 0; a < 4; ++a) {
        const int oc = oc0 + (a << 4) + (q << 2);
        float bb[4] = {b2[oc], b2[oc + 1], b2[oc + 2], b2[oc + 3]};
#pragma unroll
        for (int g = 0; g < 4; ++g) {
            const int ox = wxh + (g << 4) + m;
            float* p = out + (size_t)((((n << 7) + oc) << 7) + oy) * 128 + ox;
#pragma unroll
            for (int r = 0; r < 4; ++r)
                p[(size_t)r * 16384] += lrelu_s(acc[a][g][r] + bb[r]);
        }
    }
}

// ---------------------------------------------------------------------------
extern "C" void kernel_launch(void* const* d_in, const int* in_sizes, int n_in,
                              void* d_out, int out_size, void* d_ws, size_t ws_size,
                              hipStream_t stream)
{
    const float* x   = (const float*)d_in[0];
    const float* w1  = (const float*)d_in[1];
    const float* b1  = (const float*)d_in[2];
    const float* w2  = (const float*)d_in[3];
    const float* b2  = (const float*)d_in[4];
    const float* wsk = (const float*)d_in[5];
    float* out = (float*)d_out;

    unsigned short* xT  = (unsigned short*)d_ws;        // 8,388,608 elems
    unsigned short* t1  = xT + 8388608;                 // 8,388,608
    unsigned short* t2  = t1 + 8388608;                 // 4,194,304
    unsigned short* w1T = t2 + 4194304;                 // 589,824
    unsigned short* w2T = w1T + 589824;                 // 294,912
    unsigned short* wsT = w2T + 294912;                 // 32,768
    unsigned short* u   = wsT + 32768;                  // 33,554,432 (u-path only)
    const size_t need_u = (size_t)(8388608 + 8388608 + 4194304 + 589824 + 294912 + 32768
                                   + 33554432) * 2;     // ~110.9 MB

    k_wt3   <<<dim3(2304), 256, 0, stream>>>(w1, w1T, 589824, 1.0f / 48.0f);
    k_wt3   <<<dim3(1152), 256, 0, stream>>>(w2, w2T, 294912, 1.0f / 48.0f);
    k_wt1   <<<dim3(128),  256, 0, stream>>>(wsk, wsT, 32768, 1.0f / 16.0f);
    k_xprep <<<dim3(64, 4, 8), 256, 0, stream>>>(x, xT);
    k_conv1 <<<dim3(128, 4), 256, 0, stream>>>(xT, w1T, b1, t1);
    k_skip  <<<dim3(512), 256, 0, stream>>>(xT, wsT, t2);

    if (ws_size >= need_u) {
        k_synthu <<<dim3(2, 128, 8), 256, 0, stream>>>(t1, u);
        k_conv2u <<<dim3(512, 2), 256, 0, stream>>>(u, w2T, t2, b2, out);
    } else {
        k_upskip <<<dim3(8, 128, 8), 256, 0, stream>>>(t2, out);
        k_conv2  <<<dim3(512, 2), 256, 0, stream>>>(t1, w2T, b2, out);
    }
}

// Round 4
// 376.677 us; speedup vs baseline: 1.3376x; 1.0861x over previous
//
#include <hip/hip_runtime.h>
#include <hip/hip_bf16.h>

// ResUpBlock via bf16 MFMA implicit GEMM (fp32 accumulate).
//   xT  = channels-last bf16 copy of x              [8][64][64][256]
//   t1  = lrelu(conv3x3(x,w1/48)+b1)*sqrt2 -> bf16  [8][64][64][256] (channels-last)
//   t2  = conv1x1(x, wsk/16)              -> bf16   [8][64][64][128] (channels-last)
//   u   = upsample2x(t1)                  -> bf16   [8][128][128][256] (k_synthu)
//   out = lrelu(conv3x3(u,w2/48)+b2) + up2(t2)/sqrt2  (k_conv2u, skip fused in epilogue)
// conv1/conv2u: T14 async staging of BOTH data and weights. Weights are relaid out
// as [ocb][ci][tap][q][oc64][c8] so each chunk's 36.9KB slab is contiguous ->
// conflict-free LDS staging + fragment reads shared by all 4 waves (8x less L2
// traffic than per-wave global loads, and the MFMA phase has ZERO global ops).
// mfma_f32_16x16x32_bf16: A/B frag = 8 contiguous k per lane, C/D col=lane&15,
// row=quad*4+reg (verified per guide m89/m120).

typedef __attribute__((ext_vector_type(8))) short bf16x8;
typedef __attribute__((ext_vector_type(4))) float f32x4;

#define SQRT2F  1.41421356237309504880f
#define RSQRT2F 0.70710678118654752440f

__device__ __forceinline__ float lrelu_s(float v) { return v >= 0.f ? v : 0.2f * v; }

__device__ __forceinline__ unsigned short f2bf(float f) {
    unsigned u = __builtin_bit_cast(unsigned, f);
    u += 0x7fffu + ((u >> 16) & 1u);          // RNE
    return (unsigned short)(u >> 16);
}
__device__ __forceinline__ float bflo(unsigned u) {
    return __builtin_bit_cast(float, u << 16);
}
__device__ __forceinline__ float bfhi(unsigned u) {
    return __builtin_bit_cast(float, u & 0xffff0000u);
}

// bilinear 2x coefficients (align_corners=False, matches jax.image.resize; edge-clamped)
__device__ __forceinline__ void up2_coef(int o, int lim, int& i0, int& i1, float& w0, float& w1) {
    int h = o >> 1;
    if (o & 1) { i0 = h; i1 = (h + 1 > lim) ? lim : h + 1; w0 = 0.75f; w1 = 0.25f; }
    else       { i0 = (h - 1 < 0) ? 0 : h - 1; i1 = h;     w0 = 0.25f; w1 = 0.75f; }
}

// ---------------------------------------------------------------------------
// weight transforms
// k_wt3 output layout: [ocb][ci][tap][q][oc'][c'] (ocb=oc/64, ci=c/32, q=(c%32)/8)
// -> per (ocb,ci) a contiguous 18432-short (36.9KB) slab, staged to LDS per chunk.
// ---------------------------------------------------------------------------
__global__ __launch_bounds__(256) void k_wt3(const float* __restrict__ w,
                                             unsigned short* __restrict__ wt,
                                             int total, float scale) {
    int i = blockIdx.x * 256 + threadIdx.x;
    if (i >= total) return;
    int cp  = i & 7;
    int t1i = i >> 3;  int ocp = t1i & 63;
    int t2i = t1i >> 6; int q  = t2i & 3;
    int t3  = t2i >> 2; int tap = t3 % 9;
    int t4  = t3 / 9;   int ci  = t4 & 7; int ocb = t4 >> 3;
    int oc = (ocb << 6) + ocp;
    int c  = (ci << 5) + (q << 3) + cp;
    wt[i] = f2bf(w[(oc * 256 + c) * 9 + tap] * scale);
}

__global__ __launch_bounds__(256) void k_wt1(const float* __restrict__ w,
                                             unsigned short* __restrict__ wt,
                                             int total, float scale) {
    int i = blockIdx.x * 256 + threadIdx.x;           // [oc][c] identity layout
    if (i >= total) return;
    wt[i] = f2bf(w[i] * scale);
}

// ---------------------------------------------------------------------------
// x (NCHW f32) -> xT (channels-last bf16) via LDS transpose
// ---------------------------------------------------------------------------
__global__ __launch_bounds__(256) void k_xprep(const float* __restrict__ x,
                                               unsigned short* __restrict__ xT) {
    __shared__ float t[64][65];
    const int n = blockIdx.z, c0 = blockIdx.y << 6, p0 = blockIdx.x << 6;
    for (int i = threadIdx.x; i < 4096; i += 256) {
        int c = i >> 6, p = i & 63;
        t[c][p] = x[((size_t)(n * 256 + c0 + c) << 12) + p0 + p];
    }
    __syncthreads();
    for (int i = threadIdx.x; i < 4096; i += 256) {
        int p = i >> 6, c = i & 63;
        xT[((size_t)((n << 12) + p0 + p) << 8) + c0 + c] = f2bf(t[c][p]);
    }
}

// ---------------------------------------------------------------------------
// conv1: t1 = lrelu(conv3x3(x)+b1)*sqrt2. Data+weights T14-staged in LDS.
// block: M=64 oc x N=256 px (4 rows x 64 cols); grid dim3(128, 4)
// ---------------------------------------------------------------------------
__global__ __launch_bounds__(256, 2) void k_conv1(
    const unsigned short* __restrict__ xT, const unsigned short* __restrict__ w1T,
    const float* __restrict__ b1, unsigned short* __restrict__ t1)
{
    __shared__ __align__(16) unsigned short dt[6][66][40];   // 31.7 KB, c padded 32->40
    __shared__ __align__(16) unsigned short wl[18432];       // 36.9 KB weight slab
    const int tid = threadIdx.x;
    const int n   = blockIdx.x >> 4;
    const int y0  = (blockIdx.x & 15) << 2;
    const int ocb = blockIdx.y;
    const int oc0 = ocb << 6;
    const int w   = tid >> 6;
    const int m   = tid & 15;
    const int q   = (tid & 63) >> 4;

    f32x4 acc[4][4];
#pragma unroll
    for (int a = 0; a < 4; ++a)
#pragma unroll
        for (int g = 0; g < 4; ++g) acc[a][g] = (f32x4){0.f, 0.f, 0.f, 0.f};

    const unsigned short* wsrc = w1T + (size_t)ocb * 147456;   // 8 chunks x 18432
    const unsigned short* xTn  = xT + ((size_t)n << 20);       // n*4096*256
    unsigned short* dtf = &dt[0][0][0];

    // per-thread data staging slots: 1584 uint4 = rows 0..5 x cols 0..65 x g 0..3
    int goff[7], ldsoff[7];
#pragma unroll
    for (int k = 0; k < 7; ++k) {
        int idx = tid + (k << 8);
        goff[k] = -1; ldsoff[k] = -1;
        if (idx < 1584) {
            int r = idx / 264; int rem = idx - r * 264; int col = rem >> 2; int g = rem & 3;
            ldsoff[k] = (r * 66 + col) * 40 + (g << 3);
            int gy = y0 - 1 + r, gx = col - 1;
            if ((unsigned)gy < 64u && (unsigned)gx < 64u)
                goff[k] = (((gy << 6) + gx) << 8) + (g << 3);
        }
    }

    // prologue: issue chunk0 data + weight loads
    uint4 vreg[7];
#pragma unroll
    for (int k = 0; k < 7; ++k) {
        vreg[k] = make_uint4(0, 0, 0, 0);
        if (goff[k] >= 0) vreg[k] = *(const uint4*)(xTn + goff[k]);
    }
    uint4 wreg[9];
#pragma unroll
    for (int j = 0; j < 9; ++j)
        wreg[j] = *(const uint4*)(wsrc + ((tid + (j << 8)) << 3));

    for (int ci = 0; ci < 8; ++ci) {
        const int c0 = ci << 5;
        // drain chunk ci into LDS
#pragma unroll
        for (int k = 0; k < 7; ++k)
            if (ldsoff[k] >= 0) *(uint4*)(dtf + ldsoff[k]) = vreg[k];
#pragma unroll
        for (int j = 0; j < 9; ++j)
            *(uint4*)(wl + ((tid + (j << 8)) << 3)) = wreg[j];
        // issue chunk ci+1 loads: in flight across barrier + MFMA phase
        if (ci < 7) {
            const int cn = (ci + 1) << 5;
#pragma unroll
            for (int k = 0; k < 7; ++k)
                if (goff[k] >= 0) vreg[k] = *(const uint4*)(xTn + goff[k] + cn);
            const unsigned short* wn = wsrc + (ci + 1) * 18432;
#pragma unroll
            for (int j = 0; j < 9; ++j)
                wreg[j] = *(const uint4*)(wn + ((tid + (j << 8)) << 3));
        }
        __syncthreads();

        // pure LDS + MFMA phase (no global ops)
#pragma unroll
        for (int tap = 0; tap < 9; ++tap) {
            const int dy = tap / 3, dx = tap - 3 * (tap / 3);
            bf16x8 bfr[4];
#pragma unroll
            for (int g = 0; g < 4; ++g)
                bfr[g] = *(const bf16x8*)(&dt[w + dy][(g << 4) + m + dx][q << 3]);
#pragma unroll
            for (int a = 0; a < 4; ++a) {
                bf16x8 af = *(const bf16x8*)(wl + (((((tap << 2) + q) << 6) + (a << 4) + m) << 3));
#pragma unroll
                for (int g = 0; g < 4; ++g)
                    acc[a][g] = __builtin_amdgcn_mfma_f32_16x16x32_bf16(af, bfr[g], acc[a][g], 0, 0, 0);
            }
        }
        __syncthreads();
    }

    // epilogue: lane holds 4 consecutive oc (q*4+r) at px (g*16+m) -> 8B bf16 stores
    const int y = y0 + w;
#pragma unroll
    for (int a = 0; a < 4; ++a) {
        const int oc = oc0 + (a << 4) + (q << 2);
        float b0 = b1[oc], b1v = b1[oc + 1], b2v = b1[oc + 2], b3 = b1[oc + 3];
#pragma unroll
        for (int g = 0; g < 4; ++g) {
            const int xcol = (g << 4) + m;
            unsigned lo = (unsigned)f2bf(lrelu_s(acc[a][g][0] + b0) * SQRT2F)
                        | ((unsigned)f2bf(lrelu_s(acc[a][g][1] + b1v) * SQRT2F) << 16);
            unsigned hi = (unsigned)f2bf(lrelu_s(acc[a][g][2] + b2v) * SQRT2F)
                        | ((unsigned)f2bf(lrelu_s(acc[a][g][3] + b3) * SQRT2F) << 16);
            uint2 s; s.x = lo; s.y = hi;
            *(uint2*)(t1 + (((n << 12) + (y << 6) + xcol) << 8) + oc) = s;
        }
    }
}

// ---------------------------------------------------------------------------
// skip GEMM: t2[px][oc] = sum_c xT[px][c]*wsT[oc][c]
// ---------------------------------------------------------------------------
__global__ __launch_bounds__(256, 2) void k_skip(
    const unsigned short* __restrict__ xT, const unsigned short* __restrict__ wsT,
    unsigned short* __restrict__ t2)
{
    const int tid = threadIdx.x;
    const int w = tid >> 6, m = tid & 15, q = (tid & 63) >> 4;
    const int px0 = blockIdx.x << 6;
    const int apx = px0 + (w << 4) + m;

    f32x4 acc[8];
#pragma unroll
    for (int g = 0; g < 8; ++g) acc[g] = (f32x4){0.f, 0.f, 0.f, 0.f};

#pragma unroll
    for (int c0 = 0; c0 < 256; c0 += 32) {
        bf16x8 af = *(const bf16x8*)(xT + ((size_t)apx << 8) + c0 + (q << 3));
#pragma unroll
        for (int g = 0; g < 8; ++g) {
            bf16x8 bf = *(const bf16x8*)(wsT + (((g << 4) + m) << 8) + c0 + (q << 3));
            acc[g] = __builtin_amdgcn_mfma_f32_16x16x32_bf16(af, bf, acc[g], 0, 0, 0);
        }
    }
#pragma unroll
    for (int g = 0; g < 8; ++g) {
        const int oc = (g << 4) + m;
#pragma unroll
        for (int r = 0; r < 4; ++r) {
            int opx = px0 + (w << 4) + (q << 2) + r;
            t2[((size_t)opx << 7) + oc] = f2bf(acc[g][r]);
        }
    }
}

// ---------------------------------------------------------------------------
// k_synthu: u[n][oy][ox][c] = bilinear2x(t1), bf16 channels-last.
// grid dim3(2, 128, 8)
// ---------------------------------------------------------------------------
__global__ __launch_bounds__(256) void k_synthu(
    const unsigned short* __restrict__ t1, unsigned short* __restrict__ u)
{
    const int n = blockIdx.z, oy = blockIdx.y, x0 = blockIdx.x << 6;
    int ry0, ry1; float wy0, wy1;
    up2_coef(oy, 63, ry0, ry1, wy0, wy1);
    const unsigned short* tb = t1 + ((size_t)n << 20);           // n*4096*256
    unsigned short* ub = u + ((size_t)((n << 7) + oy) << 15);    // row = 128*256 elems

    for (int idx = threadIdx.x; idx < 2048; idx += 256) {
        const int ox = x0 + (idx >> 5), g = idx & 31;
        int cx0, cx1; float wx0, wx1;
        up2_coef(ox, 63, cx0, cx1, wx0, wx1);
        const int co = g << 3;
        uint4 v00 = *(const uint4*)(tb + (((ry0 << 6) + cx0) << 8) + co);
        uint4 v01 = *(const uint4*)(tb + (((ry0 << 6) + cx1) << 8) + co);
        uint4 v10 = *(const uint4*)(tb + (((ry1 << 6) + cx0) << 8) + co);
        uint4 v11 = *(const uint4*)(tb + (((ry1 << 6) + cx1) << 8) + co);
        const unsigned* pa = (const unsigned*)&v00; const unsigned* pb = (const unsigned*)&v01;
        const unsigned* pc = (const unsigned*)&v10; const unsigned* pd = (const unsigned*)&v11;
        uint4 res; unsigned* pr = (unsigned*)&res;
#pragma unroll
        for (int j = 0; j < 4; ++j) {
            float vlo = wy0 * (wx0 * bflo(pa[j]) + wx1 * bflo(pb[j]))
                      + wy1 * (wx0 * bflo(pc[j]) + wx1 * bflo(pd[j]));
            float vhi = wy0 * (wx0 * bfhi(pa[j]) + wx1 * bfhi(pb[j]))
                      + wy1 * (wx0 * bfhi(pc[j]) + wx1 * bfhi(pd[j]));
            pr[j] = (unsigned)f2bf(vlo) | ((unsigned)f2bf(vhi) << 16);
        }
        *(uint4*)(ub + (ox << 8) + co) = res;
    }
}

// ---------------------------------------------------------------------------
// k_conv2u: out = lrelu(conv3x3(u)+b2) + up2(t2)*RSQRT2. Data+weights T14-staged.
// block: M=64 oc x N=256 px (4 oy rows x 64 ox cols); grid dim3(512, 2)
// ---------------------------------------------------------------------------
__global__ __launch_bounds__(256, 2) void k_conv2u(
    const unsigned short* __restrict__ u, const unsigned short* __restrict__ w2T,
    const unsigned short* __restrict__ t2, const float* __restrict__ b2,
    float* __restrict__ out)
{
    __shared__ __align__(16) unsigned short dt[6][66][40];   // 31.7 KB
    __shared__ __align__(16) unsigned short wl[18432];       // 36.9 KB
    const int tid  = threadIdx.x;
    const int n    = blockIdx.x >> 6;
    const int rest = blockIdx.x & 63;
    const int oy0  = (rest >> 1) << 2;
    const int x0   = (rest & 1) << 6;
    const int ocb  = blockIdx.y;
    const int oc0  = ocb << 6;
    const int w    = tid >> 6;
    const int m    = tid & 15;
    const int q    = (tid & 63) >> 4;

    f32x4 acc[4][4];
#pragma unroll
    for (int a = 0; a < 4; ++a)
#pragma unroll
        for (int g = 0; g < 4; ++g) acc[a][g] = (f32x4){0.f, 0.f, 0.f, 0.f};

    const unsigned short* wsrc = w2T + (size_t)ocb * 147456;
    const unsigned short* ub   = u + ((size_t)n << 22);      // n*16384*256
    unsigned short* dtf = &dt[0][0][0];

    int goff[7], ldsoff[7];
#pragma unroll
    for (int k = 0; k < 7; ++k) {
        int idx = tid + (k << 8);
        goff[k] = -1; ldsoff[k] = -1;
        if (idx < 1584) {
            int r = idx / 264; int rem = idx - r * 264; int col = rem >> 2; int g = rem & 3;
            ldsoff[k] = (r * 66 + col) * 40 + (g << 3);
            int gy = oy0 - 1 + r, gx = x0 - 1 + col;
            if ((unsigned)gy < 128u && (unsigned)gx < 128u)
                goff[k] = (((gy << 7) + gx) << 8) + (g << 3);
        }
    }

    uint4 vreg[7];
#pragma unroll
    for (int k = 0; k < 7; ++k) {
        vreg[k] = make_uint4(0, 0, 0, 0);
        if (goff[k] >= 0) vreg[k] = *(const uint4*)(ub + goff[k]);
    }
    uint4 wreg[9];
#pragma unroll
    for (int j = 0; j < 9; ++j)
        wreg[j] = *(const uint4*)(wsrc + ((tid + (j << 8)) << 3));

    for (int ci = 0; ci < 8; ++ci) {
#pragma unroll
        for (int k = 0; k < 7; ++k)
            if (ldsoff[k] >= 0) *(uint4*)(dtf + ldsoff[k]) = vreg[k];
#pragma unroll
        for (int j = 0; j < 9; ++j)
            *(uint4*)(wl + ((tid + (j << 8)) << 3)) = wreg[j];
        if (ci < 7) {
            const int cn = (ci + 1) << 5;
#pragma unroll
            for (int k = 0; k < 7; ++k)
                if (goff[k] >= 0) vreg[k] = *(const uint4*)(ub + goff[k] + cn);
            const unsigned short* wn = wsrc + (ci + 1) * 18432;
#pragma unroll
            for (int j = 0; j < 9; ++j)
                wreg[j] = *(const uint4*)(wn + ((tid + (j << 8)) << 3));
        }
        __syncthreads();

#pragma unroll
        for (int tap = 0; tap < 9; ++tap) {
            const int dy = tap / 3, dx = tap - 3 * (tap / 3);
            bf16x8 bfr[4];
#pragma unroll
            for (int g = 0; g < 4; ++g)
                bfr[g] = *(const bf16x8*)(&dt[w + dy][(g << 4) + m + dx][q << 3]);
#pragma unroll
            for (int a = 0; a < 4; ++a) {
                bf16x8 af = *(const bf16x8*)(wl + (((((tap << 2) + q) << 6) + (a << 4) + m) << 3));
#pragma unroll
                for (int g = 0; g < 4; ++g)
                    acc[a][g] = __builtin_amdgcn_mfma_f32_16x16x32_bf16(af, bfr[g], acc[a][g], 0, 0, 0);
            }
        }
        __syncthreads();
    }

    // epilogue: out[n][oc][oy][ox] = lrelu(acc+b2) + up2(t2)*RSQRT2  (pure store)
    const int oy = oy0 + w;
    int ry0, ry1; float wy0, wy1;
    up2_coef(oy, 63, ry0, ry1, wy0, wy1);
    const unsigned short* t2b = t2 + ((size_t)n << 19);      // n*4096*128
#pragma unroll
    for (int a = 0; a < 4; ++a) {
        const int oc = oc0 + (a << 4) + (q << 2);
        float bb[4] = {b2[oc], b2[oc + 1], b2[oc + 2], b2[oc + 3]};
        float* pbase = out + ((size_t)(((n << 7) + oc) << 7) + oy) * 128;
#pragma unroll
        for (int g = 0; g < 4; ++g) {
            const int ox = x0 + (g << 4) + m;
            int cx0, cx1; float wx0, wx1;
            up2_coef(ox, 63, cx0, cx1, wx0, wx1);
            uint2 A = *(const uint2*)(t2b + (((ry0 << 6) + cx0) << 7) + oc);
            uint2 B = *(const uint2*)(t2b + (((ry0 << 6) + cx1) << 7) + oc);
            uint2 C = *(const uint2*)(t2b + (((ry1 << 6) + cx0) << 7) + oc);
            uint2 D = *(const uint2*)(t2b + (((ry1 << 6) + cx1) << 7) + oc);
            const unsigned* pA = (const unsigned*)&A; const unsigned* pB = (const unsigned*)&B;
            const unsigned* pC = (const unsigned*)&C; const unsigned* pD = (const unsigned*)&D;
#pragma unroll
            for (int r = 0; r < 4; ++r) {
                unsigned wa = pA[r >> 1], wb = pB[r >> 1], wc = pC[r >> 1], wd = pD[r >> 1];
                float va = (r & 1) ? bfhi(wa) : bflo(wa);
                float vb = (r & 1) ? bfhi(wb) : bflo(wb);
                float vc = (r & 1) ? bfhi(wc) : bflo(wc);
                float vd = (r & 1) ? bfhi(wd) : bflo(wd);
                float sk = wy0 * (wx0 * va + wx1 * vb) + wy1 * (wx0 * vc + wx1 * vd);
                pbase[(size_t)r * 16384 + ox] = lrelu_s(acc[a][g][r] + bb[r]) + sk * RSQRT2F;
            }
        }
    }
}

// ---------------------------------------------------------------------------
extern "C" void kernel_launch(void* const* d_in, const int* in_sizes, int n_in,
                              void* d_out, int out_size, void* d_ws, size_t ws_size,
                              hipStream_t stream)
{
    const float* x   = (const float*)d_in[0];
    const float* w1  = (const float*)d_in[1];
    const float* b1  = (const float*)d_in[2];
    const float* w2  = (const float*)d_in[3];
    const float* b2  = (const float*)d_in[4];
    const float* wsk = (const float*)d_in[5];
    float* out = (float*)d_out;

    unsigned short* xT  = (unsigned short*)d_ws;        // 8,388,608 elems
    unsigned short* t1  = xT + 8388608;                 // 8,388,608
    unsigned short* t2  = t1 + 8388608;                 // 4,194,304
    unsigned short* w1T = t2 + 4194304;                 // 589,824
    unsigned short* w2T = w1T + 589824;                 // 294,912
    unsigned short* wsT = w2T + 294912;                 // 32,768
    unsigned short* u   = wsT + 32768;                  // 33,554,432 (~110.9 MB total)

    k_wt3   <<<dim3(2304), 256, 0, stream>>>(w1, w1T, 589824, 1.0f / 48.0f);
    k_wt3   <<<dim3(1152), 256, 0, stream>>>(w2, w2T, 294912, 1.0f / 48.0f);
    k_wt1   <<<dim3(128),  256, 0, stream>>>(wsk, wsT, 32768, 1.0f / 16.0f);
    k_xprep <<<dim3(64, 4, 8), 256, 0, stream>>>(x, xT);
    k_conv1 <<<dim3(128, 4), 256, 0, stream>>>(xT, w1T, b1, t1);
    k_skip  <<<dim3(512), 256, 0, stream>>>(xT, wsT, t2);
    k_synthu<<<dim3(2, 128, 8), 256, 0, stream>>>(t1, u);
    k_conv2u<<<dim3(512, 2), 256, 0, stream>>>(u, w2T, t2, b2, out);
}

// Round 5
// 283.536 us; speedup vs baseline: 1.7771x; 1.3285x over previous
//
#include <hip/hip_runtime.h>
#include <hip/hip_bf16.h>

// ResUpBlock via bf16 MFMA implicit GEMM (fp32 accumulate).
//   xT  = channels-last bf16 copy of x              [8][64][64][256]
//   t1  = lrelu(conv3x3(x,w1/48)+b1)*sqrt2 -> bf16  [8][64][64][256] (channels-last)
//   t2  = conv1x1(x, wsk/16)              -> bf16   [8][64][64][128] (channels-last)
//   u   = upsample2x(t1)                  -> bf16   [8][128][128][256] (k_synthu)
//   out = lrelu(conv3x3(u,w2/48)+b2) + up2(t2)/sqrt2  (k_conv2u, skip fused in epilogue)
// conv1/conv2u: data T14-staged (vreg prefetch issued one chunk ahead, flies across
// the barrier + MFMA phase). Weights staged SAME-CHUNK in the drain region via
// short-lived temp regs (L2-hot ~300cy, covered by the data ds_writes) -> no
// registers live across the MFMA phase beyond vreg+acc => no spill (round-4 lesson:
// chunk-ahead wreg[9] at launch_bounds(256,2) spilled ~280MB of scratch to HBM).
// Weight layout [ocb][ci][tap][q][oc64][c8]: each chunk's 36.9KB slab contiguous ->
// coalesced staging + conflict-free (2-way) b128 fragment reads shared by all waves.
// mfma_f32_16x16x32_bf16: A/B frag = 8 contiguous k per lane, C/D col=lane&15,
// row=quad*4+reg (verified per guide m89/m120).

typedef __attribute__((ext_vector_type(8))) short bf16x8;
typedef __attribute__((ext_vector_type(4))) float f32x4;

#define SQRT2F  1.41421356237309504880f
#define RSQRT2F 0.70710678118654752440f

__device__ __forceinline__ float lrelu_s(float v) { return v >= 0.f ? v : 0.2f * v; }

__device__ __forceinline__ unsigned short f2bf(float f) {
    unsigned u = __builtin_bit_cast(unsigned, f);
    u += 0x7fffu + ((u >> 16) & 1u);          // RNE
    return (unsigned short)(u >> 16);
}
__device__ __forceinline__ float bflo(unsigned u) {
    return __builtin_bit_cast(float, u << 16);
}
__device__ __forceinline__ float bfhi(unsigned u) {
    return __builtin_bit_cast(float, u & 0xffff0000u);
}

// bilinear 2x coefficients (align_corners=False, matches jax.image.resize; edge-clamped)
__device__ __forceinline__ void up2_coef(int o, int lim, int& i0, int& i1, float& w0, float& w1) {
    int h = o >> 1;
    if (o & 1) { i0 = h; i1 = (h + 1 > lim) ? lim : h + 1; w0 = 0.75f; w1 = 0.25f; }
    else       { i0 = (h - 1 < 0) ? 0 : h - 1; i1 = h;     w0 = 0.25f; w1 = 0.75f; }
}

// ---------------------------------------------------------------------------
// weight transforms
// k_wt3 output layout: [ocb][ci][tap][q][oc'][c'] (ocb=oc/64, ci=c/32, q=(c%32)/8)
// -> per (ocb,ci) a contiguous 18432-short (36.9KB) slab, staged to LDS per chunk.
// ---------------------------------------------------------------------------
__global__ __launch_bounds__(256) void k_wt3(const float* __restrict__ w,
                                             unsigned short* __restrict__ wt,
                                             int total, float scale) {
    int i = blockIdx.x * 256 + threadIdx.x;
    if (i >= total) return;
    int cp  = i & 7;
    int t1i = i >> 3;  int ocp = t1i & 63;
    int t2i = t1i >> 6; int q  = t2i & 3;
    int t3  = t2i >> 2; int tap = t3 % 9;
    int t4  = t3 / 9;   int ci  = t4 & 7; int ocb = t4 >> 3;
    int oc = (ocb << 6) + ocp;
    int c  = (ci << 5) + (q << 3) + cp;
    wt[i] = f2bf(w[(oc * 256 + c) * 9 + tap] * scale);
}

__global__ __launch_bounds__(256) void k_wt1(const float* __restrict__ w,
                                             unsigned short* __restrict__ wt,
                                             int total, float scale) {
    int i = blockIdx.x * 256 + threadIdx.x;           // [oc][c] identity layout
    if (i >= total) return;
    wt[i] = f2bf(w[i] * scale);
}

// ---------------------------------------------------------------------------
// x (NCHW f32) -> xT (channels-last bf16) via LDS transpose
// ---------------------------------------------------------------------------
__global__ __launch_bounds__(256) void k_xprep(const float* __restrict__ x,
                                               unsigned short* __restrict__ xT) {
    __shared__ float t[64][65];
    const int n = blockIdx.z, c0 = blockIdx.y << 6, p0 = blockIdx.x << 6;
    for (int i = threadIdx.x; i < 4096; i += 256) {
        int c = i >> 6, p = i & 63;
        t[c][p] = x[((size_t)(n * 256 + c0 + c) << 12) + p0 + p];
    }
    __syncthreads();
    for (int i = threadIdx.x; i < 4096; i += 256) {
        int p = i >> 6, c = i & 63;
        xT[((size_t)((n << 12) + p0 + p) << 8) + c0 + c] = f2bf(t[c][p]);
    }
}

// ---------------------------------------------------------------------------
// conv1: t1 = lrelu(conv3x3(x)+b1)*sqrt2. Data vreg-prefetched, weights
// drain-staged same-chunk. block: M=64 oc x N=256 px; grid dim3(128, 4)
// ---------------------------------------------------------------------------
__global__ __launch_bounds__(256, 2) void k_conv1(
    const unsigned short* __restrict__ xT, const unsigned short* __restrict__ w1T,
    const float* __restrict__ b1, unsigned short* __restrict__ t1)
{
    __shared__ __align__(16) unsigned short dt[6][66][40];   // 31.7 KB, c padded 32->40
    __shared__ __align__(16) unsigned short wl[18432];       // 36.9 KB weight slab
    const int tid = threadIdx.x;
    const int n   = blockIdx.x >> 4;
    const int y0  = (blockIdx.x & 15) << 2;
    const int ocb = blockIdx.y;
    const int oc0 = ocb << 6;
    const int w   = tid >> 6;
    const int m   = tid & 15;
    const int q   = (tid & 63) >> 4;

    f32x4 acc[4][4];
#pragma unroll
    for (int a = 0; a < 4; ++a)
#pragma unroll
        for (int g = 0; g < 4; ++g) acc[a][g] = (f32x4){0.f, 0.f, 0.f, 0.f};

    const unsigned short* wsrc = w1T + (size_t)ocb * 147456;   // 8 chunks x 18432
    const unsigned short* xTn  = xT + ((size_t)n << 20);       // n*4096*256
    unsigned short* dtf = &dt[0][0][0];

    // per-thread data staging slots: 1584 uint4 = rows 0..5 x cols 0..65 x g 0..3
    int goff[7], ldsoff[7];
#pragma unroll
    for (int k = 0; k < 7; ++k) {
        int idx = tid + (k << 8);
        goff[k] = -1; ldsoff[k] = -1;
        if (idx < 1584) {
            int r = idx / 264; int rem = idx - r * 264; int col = rem >> 2; int g = rem & 3;
            ldsoff[k] = (r * 66 + col) * 40 + (g << 3);
            int gy = y0 - 1 + r, gx = col - 1;
            if ((unsigned)gy < 64u && (unsigned)gx < 64u)
                goff[k] = (((gy << 6) + gx) << 8) + (g << 3);
        }
    }

    // prologue: issue chunk0 data loads (OOB lanes stay zero forever)
    uint4 vreg[7];
#pragma unroll
    for (int k = 0; k < 7; ++k) {
        vreg[k] = make_uint4(0, 0, 0, 0);
        if (goff[k] >= 0) vreg[k] = *(const uint4*)(xTn + goff[k]);
    }

    for (int ci = 0; ci < 8; ++ci) {
        // (a) issue THIS chunk's weight slab loads (L2-hot, short-lived regs)
        uint4 twreg[9];
        const unsigned short* wc = wsrc + ci * 18432;
#pragma unroll
        for (int j = 0; j < 9; ++j)
            twreg[j] = *(const uint4*)(wc + ((tid + (j << 8)) << 3));
        // (b) drain chunk ci data into LDS (covers part of the weight L2 latency)
#pragma unroll
        for (int k = 0; k < 7; ++k)
            if (ldsoff[k] >= 0) *(uint4*)(dtf + ldsoff[k]) = vreg[k];
        // (c) issue chunk ci+1 data loads: in flight across barrier + MFMA phase
        if (ci < 7) {
            const int cn = (ci + 1) << 5;
#pragma unroll
            for (int k = 0; k < 7; ++k)
                if (goff[k] >= 0) vreg[k] = *(const uint4*)(xTn + goff[k] + cn);
        }
        // (d) weights -> LDS (twreg dies here; not live across MFMA phase)
#pragma unroll
        for (int j = 0; j < 9; ++j)
            *(uint4*)(wl + ((tid + (j << 8)) << 3)) = twreg[j];
        __syncthreads();

        // pure LDS + MFMA phase (no global ops)
#pragma unroll
        for (int tap = 0; tap < 9; ++tap) {
            const int dy = tap / 3, dx = tap - 3 * (tap / 3);
            bf16x8 bfr[4];
#pragma unroll
            for (int g = 0; g < 4; ++g)
                bfr[g] = *(const bf16x8*)(&dt[w + dy][(g << 4) + m + dx][q << 3]);
#pragma unroll
            for (int a = 0; a < 4; ++a) {
                bf16x8 af = *(const bf16x8*)(wl + (((((tap << 2) + q) << 6) + (a << 4) + m) << 3));
#pragma unroll
                for (int g = 0; g < 4; ++g)
                    acc[a][g] = __builtin_amdgcn_mfma_f32_16x16x32_bf16(af, bfr[g], acc[a][g], 0, 0, 0);
            }
        }
        __syncthreads();
    }

    // epilogue: lane holds 4 consecutive oc (q*4+r) at px (g*16+m) -> 8B bf16 stores
    const int y = y0 + w;
#pragma unroll
    for (int a = 0; a < 4; ++a) {
        const int oc = oc0 + (a << 4) + (q << 2);
        float b0 = b1[oc], b1v = b1[oc + 1], b2v = b1[oc + 2], b3 = b1[oc + 3];
#pragma unroll
        for (int g = 0; g < 4; ++g) {
            const int xcol = (g << 4) + m;
            unsigned lo = (unsigned)f2bf(lrelu_s(acc[a][g][0] + b0) * SQRT2F)
                        | ((unsigned)f2bf(lrelu_s(acc[a][g][1] + b1v) * SQRT2F) << 16);
            unsigned hi = (unsigned)f2bf(lrelu_s(acc[a][g][2] + b2v) * SQRT2F)
                        | ((unsigned)f2bf(lrelu_s(acc[a][g][3] + b3) * SQRT2F) << 16);
            uint2 s; s.x = lo; s.y = hi;
            *(uint2*)(t1 + (((n << 12) + (y << 6) + xcol) << 8) + oc) = s;
        }
    }
}

// ---------------------------------------------------------------------------
// skip GEMM: t2[px][oc] = sum_c xT[px][c]*wsT[oc][c]
// ---------------------------------------------------------------------------
__global__ __launch_bounds__(256, 2) void k_skip(
    const unsigned short* __restrict__ xT, const unsigned short* __restrict__ wsT,
    unsigned short* __restrict__ t2)
{
    const int tid = threadIdx.x;
    const int w = tid >> 6, m = tid & 15, q = (tid & 63) >> 4;
    const int px0 = blockIdx.x << 6;
    const int apx = px0 + (w << 4) + m;

    f32x4 acc[8];
#pragma unroll
    for (int g = 0; g < 8; ++g) acc[g] = (f32x4){0.f, 0.f, 0.f, 0.f};

#pragma unroll
    for (int c0 = 0; c0 < 256; c0 += 32) {
        bf16x8 af = *(const bf16x8*)(xT + ((size_t)apx << 8) + c0 + (q << 3));
#pragma unroll
        for (int g = 0; g < 8; ++g) {
            bf16x8 bf = *(const bf16x8*)(wsT + (((g << 4) + m) << 8) + c0 + (q << 3));
            acc[g] = __builtin_amdgcn_mfma_f32_16x16x32_bf16(af, bf, acc[g], 0, 0, 0);
        }
    }
#pragma unroll
    for (int g = 0; g < 8; ++g) {
        const int oc = (g << 4) + m;
#pragma unroll
        for (int r = 0; r < 4; ++r) {
            int opx = px0 + (w << 4) + (q << 2) + r;
            t2[((size_t)opx << 7) + oc] = f2bf(acc[g][r]);
        }
    }
}

// ---------------------------------------------------------------------------
// k_synthu: u[n][oy][ox][c] = bilinear2x(t1), bf16 channels-last.
// grid dim3(2, 128, 8)
// ---------------------------------------------------------------------------
__global__ __launch_bounds__(256) void k_synthu(
    const unsigned short* __restrict__ t1, unsigned short* __restrict__ u)
{
    const int n = blockIdx.z, oy = blockIdx.y, x0 = blockIdx.x << 6;
    int ry0, ry1; float wy0, wy1;
    up2_coef(oy, 63, ry0, ry1, wy0, wy1);
    const unsigned short* tb = t1 + ((size_t)n << 20);           // n*4096*256
    unsigned short* ub = u + ((size_t)((n << 7) + oy) << 15);    // row = 128*256 elems

    for (int idx = threadIdx.x; idx < 2048; idx += 256) {
        const int ox = x0 + (idx >> 5), g = idx & 31;
        int cx0, cx1; float wx0, wx1;
        up2_coef(ox, 63, cx0, cx1, wx0, wx1);
        const int co = g << 3;
        uint4 v00 = *(const uint4*)(tb + (((ry0 << 6) + cx0) << 8) + co);
        uint4 v01 = *(const uint4*)(tb + (((ry0 << 6) + cx1) << 8) + co);
        uint4 v10 = *(const uint4*)(tb + (((ry1 << 6) + cx0) << 8) + co);
        uint4 v11 = *(const uint4*)(tb + (((ry1 << 6) + cx1) << 8) + co);
        const unsigned* pa = (const unsigned*)&v00; const unsigned* pb = (const unsigned*)&v01;
        const unsigned* pc = (const unsigned*)&v10; const unsigned* pd = (const unsigned*)&v11;
        uint4 res; unsigned* pr = (unsigned*)&res;
#pragma unroll
        for (int j = 0; j < 4; ++j) {
            float vlo = wy0 * (wx0 * bflo(pa[j]) + wx1 * bflo(pb[j]))
                      + wy1 * (wx0 * bflo(pc[j]) + wx1 * bflo(pd[j]));
            float vhi = wy0 * (wx0 * bfhi(pa[j]) + wx1 * bfhi(pb[j]))
                      + wy1 * (wx0 * bfhi(pc[j]) + wx1 * bfhi(pd[j]));
            pr[j] = (unsigned)f2bf(vlo) | ((unsigned)f2bf(vhi) << 16);
        }
        *(uint4*)(ub + (ox << 8) + co) = res;
    }
}

// ---------------------------------------------------------------------------
// k_conv2u: out = lrelu(conv3x3(u)+b2) + up2(t2)*RSQRT2. Data vreg-prefetched,
// weights drain-staged same-chunk. block: M=64 oc x N=256 px; grid dim3(512, 2)
// ---------------------------------------------------------------------------
__global__ __launch_bounds__(256, 2) void k_conv2u(
    const unsigned short* __restrict__ u, const unsigned short* __restrict__ w2T,
    const unsigned short* __restrict__ t2, const float* __restrict__ b2,
    float* __restrict__ out)
{
    __shared__ __align__(16) unsigned short dt[6][66][40];   // 31.7 KB
    __shared__ __align__(16) unsigned short wl[18432];       // 36.9 KB
    const int tid  = threadIdx.x;
    const int n    = blockIdx.x >> 6;
    const int rest = blockIdx.x & 63;
    const int oy0  = (rest >> 1) << 2;
    const int x0   = (rest & 1) << 6;
    const int ocb  = blockIdx.y;
    const int oc0  = ocb << 6;
    const int w    = tid >> 6;
    const int m    = tid & 15;
    const int q    = (tid & 63) >> 4;

    f32x4 acc[4][4];
#pragma unroll
    for (int a = 0; a < 4; ++a)
#pragma unroll
        for (int g = 0; g < 4; ++g) acc[a][g] = (f32x4){0.f, 0.f, 0.f, 0.f};

    const unsigned short* wsrc = w2T + (size_t)ocb * 147456;
    const unsigned short* ub   = u + ((size_t)n << 22);      // n*16384*256
    unsigned short* dtf = &dt[0][0][0];

    int goff[7], ldsoff[7];
#pragma unroll
    for (int k = 0; k < 7; ++k) {
        int idx = tid + (k << 8);
        goff[k] = -1; ldsoff[k] = -1;
        if (idx < 1584) {
            int r = idx / 264; int rem = idx - r * 264; int col = rem >> 2; int g = rem & 3;
            ldsoff[k] = (r * 66 + col) * 40 + (g << 3);
            int gy = oy0 - 1 + r, gx = x0 - 1 + col;
            if ((unsigned)gy < 128u && (unsigned)gx < 128u)
                goff[k] = (((gy << 7) + gx) << 8) + (g << 3);
        }
    }

    uint4 vreg[7];
#pragma unroll
    for (int k = 0; k < 7; ++k) {
        vreg[k] = make_uint4(0, 0, 0, 0);
        if (goff[k] >= 0) vreg[k] = *(const uint4*)(ub + goff[k]);
    }

    for (int ci = 0; ci < 8; ++ci) {
        // (a) issue THIS chunk's weight slab loads (L2-hot, short-lived regs)
        uint4 twreg[9];
        const unsigned short* wc = wsrc + ci * 18432;
#pragma unroll
        for (int j = 0; j < 9; ++j)
            twreg[j] = *(const uint4*)(wc + ((tid + (j << 8)) << 3));
        // (b) drain chunk ci data into LDS
#pragma unroll
        for (int k = 0; k < 7; ++k)
            if (ldsoff[k] >= 0) *(uint4*)(dtf + ldsoff[k]) = vreg[k];
        // (c) issue chunk ci+1 data loads
        if (ci < 7) {
            const int cn = (ci + 1) << 5;
#pragma unroll
            for (int k = 0; k < 7; ++k)
                if (goff[k] >= 0) vreg[k] = *(const uint4*)(ub + goff[k] + cn);
        }
        // (d) weights -> LDS (twreg dies here)
#pragma unroll
        for (int j = 0; j < 9; ++j)
            *(uint4*)(wl + ((tid + (j << 8)) << 3)) = twreg[j];
        __syncthreads();

#pragma unroll
        for (int tap = 0; tap < 9; ++tap) {
            const int dy = tap / 3, dx = tap - 3 * (tap / 3);
            bf16x8 bfr[4];
#pragma unroll
            for (int g = 0; g < 4; ++g)
                bfr[g] = *(const bf16x8*)(&dt[w + dy][(g << 4) + m + dx][q << 3]);
#pragma unroll
            for (int a = 0; a < 4; ++a) {
                bf16x8 af = *(const bf16x8*)(wl + (((((tap << 2) + q) << 6) + (a << 4) + m) << 3));
#pragma unroll
                for (int g = 0; g < 4; ++g)
                    acc[a][g] = __builtin_amdgcn_mfma_f32_16x16x32_bf16(af, bfr[g], acc[a][g], 0, 0, 0);
            }
        }
        __syncthreads();
    }

    // epilogue: out[n][oc][oy][ox] = lrelu(acc+b2) + up2(t2)*RSQRT2  (pure store)
    const int oy = oy0 + w;
    int ry0, ry1; float wy0, wy1;
    up2_coef(oy, 63, ry0, ry1, wy0, wy1);
    const unsigned short* t2b = t2 + ((size_t)n << 19);      // n*4096*128
#pragma unroll
    for (int a = 0; a < 4; ++a) {
        const int oc = oc0 + (a << 4) + (q << 2);
        float bb[4] = {b2[oc], b2[oc + 1], b2[oc + 2], b2[oc + 3]};
        float* pbase = out + ((size_t)(((n << 7) + oc) << 7) + oy) * 128;
#pragma unroll
        for (int g = 0; g < 4; ++g) {
            const int ox = x0 + (g << 4) + m;
            int cx0, cx1; float wx0, wx1;
            up2_coef(ox, 63, cx0, cx1, wx0, wx1);
            uint2 A = *(const uint2*)(t2b + (((ry0 << 6) + cx0) << 7) + oc);
            uint2 B = *(const uint2*)(t2b + (((ry0 << 6) + cx1) << 7) + oc);
            uint2 C = *(const uint2*)(t2b + (((ry1 << 6) + cx0) << 7) + oc);
            uint2 D = *(const uint2*)(t2b + (((ry1 << 6) + cx1) << 7) + oc);
            const unsigned* pA = (const unsigned*)&A; const unsigned* pB = (const unsigned*)&B;
            const unsigned* pC = (const unsigned*)&C; const unsigned* pD = (const unsigned*)&D;
#pragma unroll
            for (int r = 0; r < 4; ++r) {
                unsigned wa = pA[r >> 1], wb = pB[r >> 1], wc_ = pC[r >> 1], wd = pD[r >> 1];
                float va = (r & 1) ? bfhi(wa) : bflo(wa);
                float vb = (r & 1) ? bfhi(wb) : bflo(wb);
                float vc = (r & 1) ? bfhi(wc_) : bflo(wc_);
                float vd = (r & 1) ? bfhi(wd) : bflo(wd);
                float sk = wy0 * (wx0 * va + wx1 * vb) + wy1 * (wx0 * vc + wx1 * vd);
                pbase[(size_t)r * 16384 + ox] = lrelu_s(acc[a][g][r] + bb[r]) + sk * RSQRT2F;
            }
        }
    }
}

// ---------------------------------------------------------------------------
extern "C" void kernel_launch(void* const* d_in, const int* in_sizes, int n_in,
                              void* d_out, int out_size, void* d_ws, size_t ws_size,
                              hipStream_t stream)
{
    const float* x   = (const float*)d_in[0];
    const float* w1  = (const float*)d_in[1];
    const float* b1  = (const float*)d_in[2];
    const float* w2  = (const float*)d_in[3];
    const float* b2  = (const float*)d_in[4];
    const float* wsk = (const float*)d_in[5];
    float* out = (float*)d_out;

    unsigned short* xT  = (unsigned short*)d_ws;        // 8,388,608 elems
    unsigned short* t1  = xT + 8388608;                 // 8,388,608
    unsigned short* t2  = t1 + 8388608;                 // 4,194,304
    unsigned short* w1T = t2 + 4194304;                 // 589,824
    unsigned short* w2T = w1T + 589824;                 // 294,912
    unsigned short* wsT = w2T + 294912;                 // 32,768
    unsigned short* u   = wsT + 32768;                  // 33,554,432 (~110.9 MB total)

    k_wt3   <<<dim3(2304), 256, 0, stream>>>(w1, w1T, 589824, 1.0f / 48.0f);
    k_wt3   <<<dim3(1152), 256, 0, stream>>>(w2, w2T, 294912, 1.0f / 48.0f);
    k_wt1   <<<dim3(128),  256, 0, stream>>>(wsk, wsT, 32768, 1.0f / 16.0f);
    k_xprep <<<dim3(64, 4, 8), 256, 0, stream>>>(x, xT);
    k_conv1 <<<dim3(128, 4), 256, 0, stream>>>(xT, w1T, b1, t1);
    k_skip  <<<dim3(512), 256, 0, stream>>>(xT, wsT, t2);
    k_synthu<<<dim3(2, 128, 8), 256, 0, stream>>>(t1, u);
    k_conv2u<<<dim3(512, 2), 256, 0, stream>>>(u, w2T, t2, b2, out);
}